// Round 8
// baseline (647.027 us; speedup 1.0000x reference)
//
#include <hip/hip_runtime.h>
#include <hip/hip_bf16.h>

#define N_POINTS 100000
#define K_VOL 27
#define PAIRS 60000
#define CCH 64                       // C_IN == C_OUT == 64
#define E_TOT (K_VOL * PAIRS)        // 1,620,000
#define TILES_PER_K (PAIRS / 16)     // fallback path
#define BX 64                        // fallback path
#define NWAVES 4                     // fallback path

#define RPB 64                                     // rows per output bucket
#define NBUCKETS ((N_POINTS + RPB - 1) / RPB)      // 1563
#define NBINS (NBUCKETS * K_VOL)                   // 42201
#define CAP 96                                     // bin capacity (lambda=38.4)
#define SENT 0xFFFFFFFFu

#define GRID_MAIN 782                              // <= 1024 guaranteed co-resident
#define TOTTHR (GRID_MAIN * 256)                   // 200192

// workspace layout (bytes)
#define WS_ENT 0
#define WS_CNT (NBINS * CAP * 4)                   // 16,205,184
#define WS_BAR (WS_CNT + NBINS * 4)                // barrier u32 + cursor u32 + pad
#define WS_INBF ((WS_BAR + 16 + 15) & ~15)         // 16,374,016
#define WS_WT (WS_INBF + N_POINTS * CCH * 2)       // 29,174,016
#define WS_NEED (WS_WT + K_VOL * CCH * CCH * 2)    // 29,395,200 (~28.0 MiB)

typedef __bf16 bf16x8 __attribute__((ext_vector_type(8)));
typedef __bf16 bf16x4 __attribute__((ext_vector_type(4)));
typedef float f32x4 __attribute__((ext_vector_type(4)));

// ============================ new path ============================

// ONE kernel: [phase AB] input f32->bf16 + weight transpose + pair binning
// (disjoint data, no internal ordering needed) -> [grid barrier] -> [phase C]
// bucket GEMM+MFMA-scatter with work-stealing bucket dispatch.
//
// Grid barrier legality: __launch_bounds__(256,4) caps VGPR at 128 (phase C
// measured 112) => 4 blocks/CU capacity; LDS 32KB => 5/CU; so >=1024 blocks
// co-resident >= GRID_MAIN=782. All blocks reach the barrier unconditionally.
__global__ __launch_bounds__(256, 4) void spconv_mega_kernel(
    const float* __restrict__ input, const float* __restrict__ weight,
    const int* __restrict__ in_map, const int* __restrict__ out_map,
    const float* __restrict__ bias, unsigned char* __restrict__ ws,
    float* __restrict__ out) {
  __shared__ __align__(16) unsigned char lds[4 * 8192];   // 32,768 B
  __shared__ int curb;
  const int tid = threadIdx.x;
  const int gtid = blockIdx.x * 256 + tid;

  // ---------- phase AB: prep + fill (cnt pre-zeroed by hipMemsetAsync) ----
  for (int t = gtid; t < N_POINTS * CCH / 4; t += TOTTHR) {
    float4 v = ((const float4*)input)[t];
    bf16x4 o;
    o[0] = (__bf16)v.x; o[1] = (__bf16)v.y; o[2] = (__bf16)v.z; o[3] = (__bf16)v.w;
    *(bf16x4*)(ws + WS_INBF + (size_t)t * 8) = o;
  }
  for (int t = gtid; t < K_VOL * CCH * CCH; t += TOTTHR) {
    int k = t >> 12;
    int r = t & 4095;
    int ci = r >> 6, co = r & 63;
    *(__bf16*)(ws + WS_WT + (size_t)(((k * 64 + co) << 6) + ci) * 2) =
        (__bf16)weight[t];
  }
  {
    unsigned int* cntp = (unsigned int*)(ws + WS_CNT);
    unsigned int* entp = (unsigned int*)(ws + WS_ENT);
    for (int t = gtid; t < E_TOT; t += TOTTHR) {
      int k = t / PAIRS;            // maps are [K][PAIRS] flat; t indexes directly
      int om = out_map[t];
      int im = in_map[t];
      int bin = (om >> 6) * K_VOL + k;
      unsigned int pos = atomicAdd(cntp + bin, 1u);
      if (pos < CAP)
        entp[bin * CAP + pos] =
            (unsigned int)im | ((unsigned int)(om & (RPB - 1)) << 17);
    }
  }

  // ---------- grid barrier (device-scope atomics + release/acquire fences) --
  __syncthreads();
  if (tid == 0) {
    __threadfence();                               // release my writes
    unsigned int* bar = (unsigned int*)(ws + WS_BAR);
    atomicAdd(bar, 1u);
    while (atomicAdd(bar, 0u) < (unsigned int)GRID_MAIN)
      __builtin_amdgcn_s_sleep(2);
  }
  __syncthreads();
  __threadfence();                                 // acquire others' writes

  // ---------- phase C: work-stealing bucket loop (body == verified R7) -----
  const unsigned int* cnt = (const unsigned int*)(ws + WS_CNT);
  const unsigned int* entries = (const unsigned int*)(ws + WS_ENT);
  const __bf16* inbf = (const __bf16*)(ws + WS_INBF);
  const __bf16* wt = (const __bf16*)(ws + WS_WT);
  unsigned int* cursor = (unsigned int*)(ws + WS_BAR) + 1;

  const int wave = tid >> 6, lane = tid & 63;
  const int c = lane & 15, q = lane >> 4;
  unsigned char* stage = lds + wave * 8192;
  unsigned char* pmat = stage + 4096;

  while (true) {
    __syncthreads();                 // prev bucket's reduce fully drained
    if (tid == 0) curb = (int)atomicAdd(cursor, 1u);
    __syncthreads();
    const int b = curb;
    if (b >= NBUCKETS) break;

    // zero this wave's pmat: b32 stride-1 across lanes = conflict-free
#pragma unroll
    for (int i = 0; i < 16; ++i)
      *(float*)(pmat + i * 256 + lane * 4) = 0.f;

    f32x4 acc[4][4];
#pragma unroll
    for (int rb = 0; rb < 4; ++rb)
#pragma unroll
      for (int nt = 0; nt < 4; ++nt) acc[rb][nt] = (f32x4){0.f, 0.f, 0.f, 0.f};

    for (int kb = wave; kb < K_VOL; kb += 4) {
      const int bin = b * K_VOL + kb;
      unsigned int e0 = cnt[bin];
      if (e0 == 0) continue;
      if (e0 > CAP) e0 = CAP;

      bf16x8 bfrag[4][2];
#pragma unroll
      for (int nt = 0; nt < 4; ++nt) {
        const __bf16* wrow = wt + ((kb * 64 + nt * 16 + c) << 6);
#pragma unroll
        for (int s = 0; s < 2; ++s)
          bfrag[nt][s] = *(const bf16x8*)(wrow + s * 32 + q * 8);
      }

      const unsigned int* base = entries + bin * CAP;

      for (unsigned int tb = 0; tb < e0; tb += 32) {
        const unsigned int i0 = tb + c, i1 = tb + 16 + c;
        const unsigned int ent0 = (i0 < e0) ? base[i0] : SENT;
        const unsigned int ent1 = (i1 < e0) ? base[i1] : SENT;

        // invalid entries gather row 0 (their P^T column is all-zero)
        const unsigned int r0 = (ent0 == SENT) ? 0u : (ent0 & 0x1FFFFu);
        const unsigned int r1 = (ent1 == SENT) ? 0u : (ent1 & 0x1FFFFu);
        const __bf16* ar0 = inbf + ((size_t)r0 << 6);
        const __bf16* ar1 = inbf + ((size_t)r1 << 6);
        bf16x8 a00 = *(const bf16x8*)(ar0 + q * 8);
        bf16x8 a01 = *(const bf16x8*)(ar0 + 32 + q * 8);
        bf16x8 a10 = *(const bf16x8*)(ar1 + q * 8);
        bf16x8 a11 = *(const bf16x8*)(ar1 + 32 + q * 8);

        // mark P^T[ol][m]=1 (distinct m => distinct addresses, plain b16)
        int mol0 = -1, mol1 = -1;
        if (q == 0 && ent0 != SENT) mol0 = (int)(ent0 >> 17);
        if (q == 1 && ent1 != SENT) mol1 = (int)(ent1 >> 17);
        if (mol0 >= 0) {
          int m = c;
          *(__bf16*)(pmat + mol0 * 64 + (((m >> 3) ^ (mol0 & 3)) << 4) + (m & 7) * 2) =
              (__bf16)1.0f;
        }
        if (mol1 >= 0) {
          int m = 16 + c;
          *(__bf16*)(pmat + mol1 * 64 + (((m >> 3) ^ (mol1 & 3)) << 4) + (m & 7) * 2) =
              (__bf16)1.0f;
        }

        // C1 = A x W for both 16-entry half-tiles
        f32x4 c1a[4], c1b[4];
#pragma unroll
        for (int nt = 0; nt < 4; ++nt) {
          c1a[nt] = (f32x4){0.f, 0.f, 0.f, 0.f};
          c1b[nt] = (f32x4){0.f, 0.f, 0.f, 0.f};
        }
#pragma unroll
        for (int nt = 0; nt < 4; ++nt) {
          c1a[nt] = __builtin_amdgcn_mfma_f32_16x16x32_bf16(a00, bfrag[nt][0],
                                                            c1a[nt], 0, 0, 0);
          c1a[nt] = __builtin_amdgcn_mfma_f32_16x16x32_bf16(a01, bfrag[nt][1],
                                                            c1a[nt], 0, 0, 0);
          c1b[nt] = __builtin_amdgcn_mfma_f32_16x16x32_bf16(a10, bfrag[nt][0],
                                                            c1b[nt], 0, 0, 0);
          c1b[nt] = __builtin_amdgcn_mfma_f32_16x16x32_bf16(a11, bfrag[nt][1],
                                                            c1b[nt], 0, 0, 0);
        }

        // stage C1 as bf16: [n:64][m:32], 16B-slot XOR swizzle (slot ^= n&3)
#pragma unroll
        for (int nt = 0; nt < 4; ++nt) {
          const int n = nt * 16 + c;
          const int swz = n & 3;
          const int in0 = (q & 1) * 8;
          bf16x4 h0, h1;
#pragma unroll
          for (int r = 0; r < 4; ++r) {
            h0[r] = (__bf16)c1a[nt][r];
            h1[r] = (__bf16)c1b[nt][r];
          }
          *(bf16x4*)(stage + n * 64 + (((q >> 1) ^ swz) << 4) + in0) = h0;
          *(bf16x4*)(stage + n * 64 + (((2 + (q >> 1)) ^ swz) << 4) + in0) = h1;
        }

        // scatter: acc[rb] += P^T rows [16rb,16rb+16) (16x32) x C1 (32x64)
        bf16x8 pa[4];
#pragma unroll
        for (int rb = 0; rb < 4; ++rb)
          pa[rb] = *(const bf16x8*)(pmat + (rb * 16 + c) * 64 + ((q ^ (c & 3)) << 4));
#pragma unroll
        for (int nt = 0; nt < 4; ++nt) {
          const int n = nt * 16 + c;
          const bf16x8 bb = *(const bf16x8*)(stage + n * 64 + ((q ^ (n & 3)) << 4));
#pragma unroll
          for (int rb = 0; rb < 4; ++rb)
            acc[rb][nt] = __builtin_amdgcn_mfma_f32_16x16x32_bf16(
                pa[rb], bb, acc[rb][nt], 0, 0, 0);
        }

        // unmark (restore pmat to all-zero for the next tile/bin)
        if (mol0 >= 0) {
          int m = c;
          *(__bf16*)(pmat + mol0 * 64 + (((m >> 3) ^ (mol0 & 3)) << 4) + (m & 7) * 2) =
              (__bf16)0.0f;
        }
        if (mol1 >= 0) {
          int m = 16 + c;
          *(__bf16*)(pmat + mol1 * 64 + (((m >> 3) ^ (mol1 & 3)) << 4) + (m & 7) * 2) =
              (__bf16)0.0f;
        }
      }
    }

    // ---- cross-wave reduce: 4 partial 64x64 f32 tiles -> wave 0, store ----
    __syncthreads();
    float* bufA = (float*)lds;              // 16 KB
    float* bufB = (float*)(lds + 16384);    // 16 KB

    auto REDST = [&](float* buf) {
#pragma unroll
      for (int rb = 0; rb < 4; ++rb)
#pragma unroll
        for (int nt = 0; nt < 4; ++nt)
#pragma unroll
          for (int r = 0; r < 4; ++r) {
            int row = rb * 16 + q * 4 + r;
            int col = (nt * 16 + c) ^ (q << 2) ^ ((q & 1) << 4);
            buf[row * 64 + col] = acc[rb][nt][r];
          }
    };
    auto REDADD = [&](const float* buf) {
#pragma unroll
      for (int rb = 0; rb < 4; ++rb)
#pragma unroll
        for (int nt = 0; nt < 4; ++nt)
#pragma unroll
          for (int r = 0; r < 4; ++r) {
            int row = rb * 16 + q * 4 + r;
            int col = (nt * 16 + c) ^ (q << 2) ^ ((q & 1) << 4);
            acc[rb][nt][r] += buf[row * 64 + col];
          }
    };

    if (wave == 1) REDST(bufA);
    if (wave == 3) REDST(bufB);
    __syncthreads();
    if (wave == 0) REDADD(bufA);
    if (wave == 2) REDADD(bufB);
    __syncthreads();
    if (wave == 2) REDST(bufA);
    __syncthreads();
    if (wave == 0) {
      REDADD(bufA);
      float bv[4];
#pragma unroll
      for (int nt = 0; nt < 4; ++nt) bv[nt] = bias[nt * 16 + c];
#pragma unroll
      for (int rb = 0; rb < 4; ++rb)
#pragma unroll
        for (int r = 0; r < 4; ++r) {
          const int row = b * RPB + rb * 16 + q * 4 + r;
          if (row < N_POINTS) {
#pragma unroll
            for (int nt = 0; nt < 4; ++nt)
              out[row * CCH + nt * 16 + c] = acc[rb][nt][r] + bv[nt];
          }
        }
    }
  }
}

// ============================ fallback path (original) ============================

__global__ __launch_bounds__(256) void init_out_kernel(
    const float* __restrict__ bias, float* __restrict__ out) {
  int tid = blockIdx.x * blockDim.x + threadIdx.x;
  int c4 = tid & 15;
  float4 b = ((const float4*)bias)[c4];
  ((float4*)out)[tid] = b;
}

__global__ __launch_bounds__(256) void spconv_kernel(
    const float* __restrict__ input, const float* __restrict__ weight,
    const int* __restrict__ in_map, const int* __restrict__ out_map,
    float* __restrict__ out) {
  const int k = blockIdx.y;
  const int lane = threadIdx.x & 63;
  const int wave = threadIdx.x >> 6;
  const int col = lane & 15;
  const int quad = lane >> 4;

  const float* Wk = weight + k * (CCH * CCH);
  bf16x8 bfrag[4][2];
#pragma unroll
  for (int nt = 0; nt < 4; ++nt) {
    int co = nt * 16 + col;
#pragma unroll
    for (int s = 0; s < 2; ++s) {
      int ci0 = s * 32 + quad * 8;
      bf16x8 f;
#pragma unroll
      for (int j = 0; j < 8; ++j) f[j] = (__bf16)Wk[(ci0 + j) * CCH + co];
      bfrag[nt][s] = f;
    }
  }

  const int* im = in_map + k * PAIRS;
  const int* om = out_map + k * PAIRS;

  for (int tile = blockIdx.x * NWAVES + wave; tile < TILES_PER_K;
       tile += BX * NWAVES) {
    const int pbase = tile * 16;
    int rin = im[pbase + col];
    const float* arow = input + rin * CCH;
    bf16x8 afrag[2];
#pragma unroll
    for (int s = 0; s < 2; ++s) {
      const float4 x0 = *(const float4*)(arow + s * 32 + quad * 8);
      const float4 x1 = *(const float4*)(arow + s * 32 + quad * 8 + 4);
      bf16x8 f;
      f[0] = (__bf16)x0.x; f[1] = (__bf16)x0.y;
      f[2] = (__bf16)x0.z; f[3] = (__bf16)x0.w;
      f[4] = (__bf16)x1.x; f[5] = (__bf16)x1.y;
      f[6] = (__bf16)x1.z; f[7] = (__bf16)x1.w;
      afrag[s] = f;
    }

    f32x4 acc[4];
#pragma unroll
    for (int nt = 0; nt < 4; ++nt) acc[nt] = (f32x4){0.f, 0.f, 0.f, 0.f};
#pragma unroll
    for (int nt = 0; nt < 4; ++nt) {
      acc[nt] = __builtin_amdgcn_mfma_f32_16x16x32_bf16(afrag[0], bfrag[nt][0],
                                                        acc[nt], 0, 0, 0);
      acc[nt] = __builtin_amdgcn_mfma_f32_16x16x32_bf16(afrag[1], bfrag[nt][1],
                                                        acc[nt], 0, 0, 0);
    }

    int orow[4];
#pragma unroll
    for (int r = 0; r < 4; ++r) orow[r] = om[pbase + quad * 4 + r];
#pragma unroll
    for (int r = 0; r < 4; ++r) {
      float* op = out + orow[r] * CCH + col;
#pragma unroll
      for (int nt = 0; nt < 4; ++nt) atomicAdd(op + nt * 16, acc[nt][r]);
    }
  }
}

// ============================ launch ============================

extern "C" void kernel_launch(void* const* d_in, const int* in_sizes, int n_in,
                              void* d_out, int out_size, void* d_ws,
                              size_t ws_size, hipStream_t stream) {
  const float* input = (const float*)d_in[0];
  const float* weight = (const float*)d_in[1];
  const float* bias = (const float*)d_in[2];
  const int* in_map = (const int*)d_in[3];
  const int* out_map = (const int*)d_in[4];
  float* out = (float*)d_out;

  if (d_ws != nullptr && ws_size >= (size_t)WS_NEED) {
    unsigned char* ws = (unsigned char*)d_ws;
    // zero bin counters + barrier word + steal cursor (one small memset)
    hipMemsetAsync(ws + WS_CNT, 0, NBINS * 4 + 16, stream);
    spconv_mega_kernel<<<GRID_MAIN, 256, 0, stream>>>(input, weight, in_map,
                                                      out_map, bias, ws, out);
  } else {
    init_out_kernel<<<(N_POINTS * 16) / 256, 256, 0, stream>>>(bias, out);
    dim3 grid(BX, K_VOL);
    spconv_kernel<<<grid, 256, 0, stream>>>(input, weight, in_map, out_map, out);
  }
}

// Round 9
// 478.987 us; speedup vs baseline: 1.3508x; 1.3508x over previous
//
#include <hip/hip_runtime.h>
#include <hip/hip_bf16.h>

#define N_POINTS 100000
#define K_VOL 27
#define PAIRS 60000
#define CCH 64                       // C_IN == C_OUT == 64
#define E_TOT (K_VOL * PAIRS)        // 1,620,000
#define TILES_PER_K (PAIRS / 16)     // fallback path
#define BX 64                        // fallback path
#define NWAVES 4                     // fallback path

#define RPB 64                                     // rows per output bucket
#define NBUCKETS ((N_POINTS + RPB - 1) / RPB)      // 1563
#define NBINS (NBUCKETS * K_VOL)                   // 42201
#define CAP 96                                     // bin capacity (lambda=38.4)
#define SENT 0xFFFFFFFFu

// Grid sizing for the in-kernel barrier: phase C needs ~176 unified regs
// (112 VGPR + 64 AGPR acc) -> 2 waves/SIMD -> 2 blocks/CU; LDS 32.8KB -> 4/CU.
// 2 x 256 CU = 512 blocks GUARANTEED co-resident. Do NOT add a min-waves
// launch bound: capping unified regs below ~176 spills the accumulators
// (R8: VGPR 64, 668MB scratch writes, 4.6x slowdown).
#define GRID_MAIN 512
#define TOTTHR (GRID_MAIN * 256)                   // 131072

// workspace layout (bytes)
#define WS_ENT 0
#define WS_CNT (NBINS * CAP * 4)                   // 16,205,184
#define WS_BAR (WS_CNT + NBINS * 4)                // 2 barrier u32 + cursor u32
#define WS_INBF ((WS_BAR + 16 + 15) & ~15)         // 16,374,016
#define WS_WT (WS_INBF + N_POINTS * CCH * 2)       // 29,174,016
#define WS_NEED (WS_WT + K_VOL * CCH * CCH * 2)    // 29,395,200 (~28.0 MiB)

typedef __bf16 bf16x8 __attribute__((ext_vector_type(8)));
typedef __bf16 bf16x4 __attribute__((ext_vector_type(4)));
typedef float f32x4 __attribute__((ext_vector_type(4)));

// ============================ new path ============================

__device__ __forceinline__ void grid_barrier(unsigned int* bar) {
  __syncthreads();
  if (threadIdx.x == 0) {
    __threadfence();                               // release my block's writes
    atomicAdd(bar, 1u);
    while (atomicAdd(bar, 0u) < (unsigned int)GRID_MAIN)
      __builtin_amdgcn_s_sleep(2);
  }
  __syncthreads();
  __threadfence();                                 // acquire others' writes
}

// ONE kernel, three phases:
//  A: input f32->bf16, weight transpose, zero bin counters
//  B: bin the 1.62M pairs (bump-allocate, fixed CAP)
//  C: per-bucket GEMM + MFMA-scatter with work-stealing (verified R7/R8 body)
__global__ __launch_bounds__(256) void spconv_mega_kernel(
    const float* __restrict__ input, const float* __restrict__ weight,
    const int* __restrict__ in_map, const int* __restrict__ out_map,
    const float* __restrict__ bias, unsigned char* __restrict__ ws,
    float* __restrict__ out) {
  __shared__ __align__(16) unsigned char lds[4 * 8192];   // 32,768 B
  __shared__ int curb;
  const int tid = threadIdx.x;
  const int gtid = blockIdx.x * 256 + tid;
  unsigned int* barwords = (unsigned int*)(ws + WS_BAR);  // pre-zeroed (16B memset)

  // ---------- phase A ------------------------------------------------------
  for (int t = gtid; t < N_POINTS * CCH / 4; t += TOTTHR) {
    float4 v = ((const float4*)input)[t];
    bf16x4 o;
    o[0] = (__bf16)v.x; o[1] = (__bf16)v.y; o[2] = (__bf16)v.z; o[3] = (__bf16)v.w;
    *(bf16x4*)(ws + WS_INBF + (size_t)t * 8) = o;
  }
  for (int t = gtid; t < K_VOL * CCH * CCH; t += TOTTHR) {
    int k = t >> 12;
    int r = t & 4095;
    int ci = r >> 6, co = r & 63;
    *(__bf16*)(ws + WS_WT + (size_t)(((k * 64 + co) << 6) + ci) * 2) =
        (__bf16)weight[t];
  }
  for (int t = gtid; t < NBINS; t += TOTTHR)
    ((unsigned int*)(ws + WS_CNT))[t] = 0u;

  grid_barrier(barwords);            // cnt zeros + staged data visible

  // ---------- phase B ------------------------------------------------------
  {
    unsigned int* cntp = (unsigned int*)(ws + WS_CNT);
    unsigned int* entp = (unsigned int*)(ws + WS_ENT);
    for (int t = gtid; t < E_TOT; t += TOTTHR) {
      int k = t / PAIRS;             // maps are [K][PAIRS] flat
      int om = out_map[t];
      int im = in_map[t];
      int bin = (om >> 6) * K_VOL + k;
      unsigned int pos = atomicAdd(cntp + bin, 1u);
      if (pos < CAP)
        entp[bin * CAP + pos] =
            (unsigned int)im | ((unsigned int)(om & (RPB - 1)) << 17);
    }
  }

  grid_barrier(barwords + 1);        // bins complete & visible

  // ---------- phase C: work-stealing bucket loop (verified R7/R8 body) -----
  const unsigned int* cnt = (const unsigned int*)(ws + WS_CNT);
  const unsigned int* entries = (const unsigned int*)(ws + WS_ENT);
  const __bf16* inbf = (const __bf16*)(ws + WS_INBF);
  const __bf16* wt = (const __bf16*)(ws + WS_WT);
  unsigned int* cursor = barwords + 2;

  const int wave = tid >> 6, lane = tid & 63;
  const int c = lane & 15, q = lane >> 4;
  unsigned char* stage = lds + wave * 8192;
  unsigned char* pmat = stage + 4096;

  while (true) {
    __syncthreads();                 // prev bucket's reduce fully drained
    if (tid == 0) curb = (int)atomicAdd(cursor, 1u);
    __syncthreads();
    const int b = curb;
    if (b >= NBUCKETS) break;

    // zero this wave's pmat: b32 stride-1 across lanes = conflict-free
#pragma unroll
    for (int i = 0; i < 16; ++i)
      *(float*)(pmat + i * 256 + lane * 4) = 0.f;

    f32x4 acc[4][4];
#pragma unroll
    for (int rb = 0; rb < 4; ++rb)
#pragma unroll
      for (int nt = 0; nt < 4; ++nt) acc[rb][nt] = (f32x4){0.f, 0.f, 0.f, 0.f};

    for (int kb = wave; kb < K_VOL; kb += 4) {
      const int bin = b * K_VOL + kb;
      unsigned int e0 = cnt[bin];
      if (e0 == 0) continue;
      if (e0 > CAP) e0 = CAP;

      bf16x8 bfrag[4][2];
#pragma unroll
      for (int nt = 0; nt < 4; ++nt) {
        const __bf16* wrow = wt + ((kb * 64 + nt * 16 + c) << 6);
#pragma unroll
        for (int s = 0; s < 2; ++s)
          bfrag[nt][s] = *(const bf16x8*)(wrow + s * 32 + q * 8);
      }

      const unsigned int* base = entries + bin * CAP;

      for (unsigned int tb = 0; tb < e0; tb += 32) {
        const unsigned int i0 = tb + c, i1 = tb + 16 + c;
        const unsigned int ent0 = (i0 < e0) ? base[i0] : SENT;
        const unsigned int ent1 = (i1 < e0) ? base[i1] : SENT;

        // invalid entries gather row 0 (their P^T column is all-zero)
        const unsigned int r0 = (ent0 == SENT) ? 0u : (ent0 & 0x1FFFFu);
        const unsigned int r1 = (ent1 == SENT) ? 0u : (ent1 & 0x1FFFFu);
        const __bf16* ar0 = inbf + ((size_t)r0 << 6);
        const __bf16* ar1 = inbf + ((size_t)r1 << 6);
        bf16x8 a00 = *(const bf16x8*)(ar0 + q * 8);
        bf16x8 a01 = *(const bf16x8*)(ar0 + 32 + q * 8);
        bf16x8 a10 = *(const bf16x8*)(ar1 + q * 8);
        bf16x8 a11 = *(const bf16x8*)(ar1 + 32 + q * 8);

        // mark P^T[ol][m]=1 (distinct m => distinct addresses, plain b16)
        int mol0 = -1, mol1 = -1;
        if (q == 0 && ent0 != SENT) mol0 = (int)(ent0 >> 17);
        if (q == 1 && ent1 != SENT) mol1 = (int)(ent1 >> 17);
        if (mol0 >= 0) {
          int m = c;
          *(__bf16*)(pmat + mol0 * 64 + (((m >> 3) ^ (mol0 & 3)) << 4) + (m & 7) * 2) =
              (__bf16)1.0f;
        }
        if (mol1 >= 0) {
          int m = 16 + c;
          *(__bf16*)(pmat + mol1 * 64 + (((m >> 3) ^ (mol1 & 3)) << 4) + (m & 7) * 2) =
              (__bf16)1.0f;
        }

        // C1 = A x W for both 16-entry half-tiles
        f32x4 c1a[4], c1b[4];
#pragma unroll
        for (int nt = 0; nt < 4; ++nt) {
          c1a[nt] = (f32x4){0.f, 0.f, 0.f, 0.f};
          c1b[nt] = (f32x4){0.f, 0.f, 0.f, 0.f};
        }
#pragma unroll
        for (int nt = 0; nt < 4; ++nt) {
          c1a[nt] = __builtin_amdgcn_mfma_f32_16x16x32_bf16(a00, bfrag[nt][0],
                                                            c1a[nt], 0, 0, 0);
          c1a[nt] = __builtin_amdgcn_mfma_f32_16x16x32_bf16(a01, bfrag[nt][1],
                                                            c1a[nt], 0, 0, 0);
          c1b[nt] = __builtin_amdgcn_mfma_f32_16x16x32_bf16(a10, bfrag[nt][0],
                                                            c1b[nt], 0, 0, 0);
          c1b[nt] = __builtin_amdgcn_mfma_f32_16x16x32_bf16(a11, bfrag[nt][1],
                                                            c1b[nt], 0, 0, 0);
        }

        // stage C1 as bf16: [n:64][m:32], 16B-slot XOR swizzle (slot ^= n&3)
#pragma unroll
        for (int nt = 0; nt < 4; ++nt) {
          const int n = nt * 16 + c;
          const int swz = n & 3;
          const int in0 = (q & 1) * 8;
          bf16x4 h0, h1;
#pragma unroll
          for (int r = 0; r < 4; ++r) {
            h0[r] = (__bf16)c1a[nt][r];
            h1[r] = (__bf16)c1b[nt][r];
          }
          *(bf16x4*)(stage + n * 64 + (((q >> 1) ^ swz) << 4) + in0) = h0;
          *(bf16x4*)(stage + n * 64 + (((2 + (q >> 1)) ^ swz) << 4) + in0) = h1;
        }

        // scatter: acc[rb] += P^T rows [16rb,16rb+16) (16x32) x C1 (32x64)
        bf16x8 pa[4];
#pragma unroll
        for (int rb = 0; rb < 4; ++rb)
          pa[rb] = *(const bf16x8*)(pmat + (rb * 16 + c) * 64 + ((q ^ (c & 3)) << 4));
#pragma unroll
        for (int nt = 0; nt < 4; ++nt) {
          const int n = nt * 16 + c;
          const bf16x8 bb = *(const bf16x8*)(stage + n * 64 + ((q ^ (n & 3)) << 4));
#pragma unroll
          for (int rb = 0; rb < 4; ++rb)
            acc[rb][nt] = __builtin_amdgcn_mfma_f32_16x16x32_bf16(
                pa[rb], bb, acc[rb][nt], 0, 0, 0);
        }

        // unmark (restore pmat to all-zero for the next tile/bin)
        if (mol0 >= 0) {
          int m = c;
          *(__bf16*)(pmat + mol0 * 64 + (((m >> 3) ^ (mol0 & 3)) << 4) + (m & 7) * 2) =
              (__bf16)0.0f;
        }
        if (mol1 >= 0) {
          int m = 16 + c;
          *(__bf16*)(pmat + mol1 * 64 + (((m >> 3) ^ (mol1 & 3)) << 4) + (m & 7) * 2) =
              (__bf16)0.0f;
        }
      }
    }

    // ---- cross-wave reduce: 4 partial 64x64 f32 tiles -> wave 0, store ----
    __syncthreads();
    float* bufA = (float*)lds;              // 16 KB
    float* bufB = (float*)(lds + 16384);    // 16 KB

    auto REDST = [&](float* buf) {
#pragma unroll
      for (int rb = 0; rb < 4; ++rb)
#pragma unroll
        for (int nt = 0; nt < 4; ++nt)
#pragma unroll
          for (int r = 0; r < 4; ++r) {
            int row = rb * 16 + q * 4 + r;
            int col = (nt * 16 + c) ^ (q << 2) ^ ((q & 1) << 4);
            buf[row * 64 + col] = acc[rb][nt][r];
          }
    };
    auto REDADD = [&](const float* buf) {
#pragma unroll
      for (int rb = 0; rb < 4; ++rb)
#pragma unroll
        for (int nt = 0; nt < 4; ++nt)
#pragma unroll
          for (int r = 0; r < 4; ++r) {
            int row = rb * 16 + q * 4 + r;
            int col = (nt * 16 + c) ^ (q << 2) ^ ((q & 1) << 4);
            acc[rb][nt][r] += buf[row * 64 + col];
          }
    };

    if (wave == 1) REDST(bufA);
    if (wave == 3) REDST(bufB);
    __syncthreads();
    if (wave == 0) REDADD(bufA);
    if (wave == 2) REDADD(bufB);
    __syncthreads();
    if (wave == 2) REDST(bufA);
    __syncthreads();
    if (wave == 0) {
      REDADD(bufA);
      float bv[4];
#pragma unroll
      for (int nt = 0; nt < 4; ++nt) bv[nt] = bias[nt * 16 + c];
#pragma unroll
      for (int rb = 0; rb < 4; ++rb)
#pragma unroll
        for (int r = 0; r < 4; ++r) {
          const int row = b * RPB + rb * 16 + q * 4 + r;
          if (row < N_POINTS) {
#pragma unroll
            for (int nt = 0; nt < 4; ++nt)
              out[row * CCH + nt * 16 + c] = acc[rb][nt][r] + bv[nt];
          }
        }
    }
  }
}

// ============================ fallback path (original) ============================

__global__ __launch_bounds__(256) void init_out_kernel(
    const float* __restrict__ bias, float* __restrict__ out) {
  int tid = blockIdx.x * blockDim.x + threadIdx.x;
  int c4 = tid & 15;
  float4 b = ((const float4*)bias)[c4];
  ((float4*)out)[tid] = b;
}

__global__ __launch_bounds__(256) void spconv_kernel(
    const float* __restrict__ input, const float* __restrict__ weight,
    const int* __restrict__ in_map, const int* __restrict__ out_map,
    float* __restrict__ out) {
  const int k = blockIdx.y;
  const int lane = threadIdx.x & 63;
  const int wave = threadIdx.x >> 6;
  const int col = lane & 15;
  const int quad = lane >> 4;

  const float* Wk = weight + k * (CCH * CCH);
  bf16x8 bfrag[4][2];
#pragma unroll
  for (int nt = 0; nt < 4; ++nt) {
    int co = nt * 16 + col;
#pragma unroll
    for (int s = 0; s < 2; ++s) {
      int ci0 = s * 32 + quad * 8;
      bf16x8 f;
#pragma unroll
      for (int j = 0; j < 8; ++j) f[j] = (__bf16)Wk[(ci0 + j) * CCH + co];
      bfrag[nt][s] = f;
    }
  }

  const int* im = in_map + k * PAIRS;
  const int* om = out_map + k * PAIRS;

  for (int tile = blockIdx.x * NWAVES + wave; tile < TILES_PER_K;
       tile += BX * NWAVES) {
    const int pbase = tile * 16;
    int rin = im[pbase + col];
    const float* arow = input + rin * CCH;
    bf16x8 afrag[2];
#pragma unroll
    for (int s = 0; s < 2; ++s) {
      const float4 x0 = *(const float4*)(arow + s * 32 + quad * 8);
      const float4 x1 = *(const float4*)(arow + s * 32 + quad * 8 + 4);
      bf16x8 f;
      f[0] = (__bf16)x0.x; f[1] = (__bf16)x0.y;
      f[2] = (__bf16)x0.z; f[3] = (__bf16)x0.w;
      f[4] = (__bf16)x1.x; f[5] = (__bf16)x1.y;
      f[6] = (__bf16)x1.z; f[7] = (__bf16)x1.w;
      afrag[s] = f;
    }

    f32x4 acc[4];
#pragma unroll
    for (int nt = 0; nt < 4; ++nt) acc[nt] = (f32x4){0.f, 0.f, 0.f, 0.f};
#pragma unroll
    for (int nt = 0; nt < 4; ++nt) {
      acc[nt] = __builtin_amdgcn_mfma_f32_16x16x32_bf16(afrag[0], bfrag[nt][0],
                                                        acc[nt], 0, 0, 0);
      acc[nt] = __builtin_amdgcn_mfma_f32_16x16x32_bf16(afrag[1], bfrag[nt][1],
                                                        acc[nt], 0, 0, 0);
    }

    int orow[4];
#pragma unroll
    for (int r = 0; r < 4; ++r) orow[r] = om[pbase + quad * 4 + r];
#pragma unroll
    for (int r = 0; r < 4; ++r) {
      float* op = out + orow[r] * CCH + col;
#pragma unroll
      for (int nt = 0; nt < 4; ++nt) atomicAdd(op + nt * 16, acc[nt][r]);
    }
  }
}

// ============================ launch ============================

extern "C" void kernel_launch(void* const* d_in, const int* in_sizes, int n_in,
                              void* d_out, int out_size, void* d_ws,
                              size_t ws_size, hipStream_t stream) {
  const float* input = (const float*)d_in[0];
  const float* weight = (const float*)d_in[1];
  const float* bias = (const float*)d_in[2];
  const int* in_map = (const int*)d_in[3];
  const int* out_map = (const int*)d_in[4];
  float* out = (float*)d_out;

  if (d_ws != nullptr && ws_size >= (size_t)WS_NEED) {
    unsigned char* ws = (unsigned char*)d_ws;
    // zero ONLY the 2 barrier words + steal cursor (16 B); counters are
    // zeroed inside phase A of the mega-kernel.
    hipMemsetAsync(ws + WS_BAR, 0, 16, stream);
    spconv_mega_kernel<<<GRID_MAIN, 256, 0, stream>>>(input, weight, in_map,
                                                      out_map, bias, ws, out);
  } else {
    init_out_kernel<<<(N_POINTS * 16) / 256, 256, 0, stream>>>(bias, out);
    dim3 grid(BX, K_VOL);
    spconv_kernel<<<grid, 256, 0, stream>>>(input, weight, in_map, out_map, out);
  }
}

// Round 10
// 286.999 us; speedup vs baseline: 2.2545x; 1.6690x over previous
//
#include <hip/hip_runtime.h>
#include <hip/hip_bf16.h>

#define N_POINTS 100000
#define K_VOL 27
#define PAIRS 60000
#define CCH 64                       // C_IN == C_OUT == 64
#define TILES_PER_K (PAIRS / 16)     // fallback path
#define BX 64                        // fallback path
#define NWAVES 4                     // fallback path

#define RPB 64                                     // rows per output bucket
#define NBUCKETS ((N_POINTS + RPB - 1) / RPB)      // 1563
#define NBINS (NBUCKETS * K_VOL)                   // 42201
#define CAP 96                                     // bin capacity (lambda=38.4)
#define SENT 0xFFFFFFFFu
#define CNTSTRIDE 32                               // counters padded to 128B/bucket

#define PREP_BLKS 6250                             // 1.6M threads for input cvt
#define FILL_BLKS (K_VOL * 64)                     // 1728: per k, 8 slices x 8 subs
#define PSUB (PAIRS / 8)                           // 7500 pairs per sub-range

// workspace layout (bytes)
#define WS_ENT 0
#define WS_CNT (NBINS * CAP * 4)                   // 16,205,184 (128B-aligned)
#define WS_INBF (WS_CNT + NBUCKETS * CNTSTRIDE * 4) // 16,405,248
#define WS_WT (WS_INBF + N_POINTS * CCH * 2)       // 29,205,248
#define WS_NEED (WS_WT + K_VOL * CCH * CCH * 2)    // 29,426,432 (~28.1 MiB)

typedef __bf16 bf16x8 __attribute__((ext_vector_type(8)));
typedef __bf16 bf16x4 __attribute__((ext_vector_type(4)));
typedef float f32x4 __attribute__((ext_vector_type(4)));

// ============================ new path ============================

// Fused prep + XCD-local fill (counters pre-zeroed by hipMemsetAsync).
//
// prep blocks [0,PREP_BLKS): input f32->bf16; weight -> bf16 wt[k][co][ci].
// fill blocks: f = bid-PREP_BLKS in [0, 27*64): k = f>>6, bx = f&63,
//   slice = bx&7, sub = bx>>3. The block scans p in [sub*7500,(sub+1)*7500)
//   of k's row and bins ONLY pairs whose bucket (om>>6) has bucket&7 == slice.
//   Since consecutive flat block ids round-robin across the 8 XCDs, all
//   blocks of one slice run on ONE XCD; a bucket's counter line (128B
//   padded) and entry region (10368B, 128B-aligned) are touched only by
//   that XCD -> bin atomics/writes stay L2-resident instead of bouncing
//   across XCDs (R9 evidence: fabric-bounced binning cost ~200us).
//   Mapping is a perf heuristic only -- any block->XCD mapping is correct.
// Cost: maps are read 8x (104MB streaming, ~20us) -- a good trade.
// entry = in_row (17b) | out_local (6b) << 17
__global__ __launch_bounds__(256) void prep_fill_kernel(
    const float* __restrict__ input, const float* __restrict__ weight,
    const int* __restrict__ in_map, const int* __restrict__ out_map,
    unsigned char* __restrict__ ws) {
  const int bid = blockIdx.x;
  if (bid < PREP_BLKS) {
    int t = bid * 256 + threadIdx.x;  // exactly N*CCH/4 = 1,600,000 threads
    float4 v = ((const float4*)input)[t];
    bf16x4 o;
    o[0] = (__bf16)v.x; o[1] = (__bf16)v.y; o[2] = (__bf16)v.z; o[3] = (__bf16)v.w;
    *(bf16x4*)(ws + WS_INBF + (size_t)t * 8) = o;
    if (t < K_VOL * CCH * CCH) {             // 110592
      int k = t >> 12;
      int r = t & 4095;
      int ci = r >> 6, co = r & 63;
      *(__bf16*)(ws + WS_WT + (size_t)(((k * 64 + co) << 6) + ci) * 2) =
          (__bf16)weight[t];
    }
  } else {
    const int f = bid - PREP_BLKS;           // [0, 1728)
    const int k = f >> 6;
    const int bx = f & 63;
    const int slice = bx & 7;
    const int sub = bx >> 3;
    const int pbeg = sub * PSUB, pend = pbeg + PSUB;
    const int* omp_ = out_map + k * PAIRS;
    const int* imp_ = in_map + k * PAIRS;
    unsigned int* cntp = (unsigned int*)(ws + WS_CNT);
    unsigned int* entp = (unsigned int*)(ws + WS_ENT);
    for (int p = pbeg + (int)threadIdx.x * 4; p < pend; p += 1024) {
      int4 om4 = *(const int4*)(omp_ + p);
      int4 im4 = *(const int4*)(imp_ + p);
      int oms[4] = {om4.x, om4.y, om4.z, om4.w};
      int ims[4] = {im4.x, im4.y, im4.z, im4.w};
#pragma unroll
      for (int j = 0; j < 4; ++j) {
        int bkt = oms[j] >> 6;
        if ((bkt & 7) != slice) continue;
        unsigned int pos = atomicAdd(cntp + (bkt << 5) + k, 1u);
        if (pos < CAP)
          entp[(bkt * K_VOL + k) * CAP + pos] =
              (unsigned int)ims[j] | ((unsigned int)(oms[j] & 63) << 17);
      }
    }
  }
}

// One block per 64-row bucket (verified R7 body; only cnt stride changed).
// Wave w owns ALL 64 rows but only k-bins {w, w+4, ...} -> 1x redundancy.
// Per 32-entry tile: C1 = gather(A) x W (8 MFMA) -> bf16 LDS stage;
// P^T (64x32 0/1, persistent LDS, mark/unmark); acc += P^T x C1 (16 MFMA).
// Cross-wave LDS tree-reduce, single coalesced store + bias.
// NOTE: no min-waves bound -- acc(64 AGPR)+bfrag(32)+temps ~176 unified regs;
// capping below that spills the accumulators (R8: 4.6x slowdown).
__global__ __launch_bounds__(256) void spconv_main_kernel(
    const float* __restrict__ bias, const unsigned char* __restrict__ ws,
    float* __restrict__ out) {
  __shared__ __align__(16) unsigned char lds[4 * 8192];   // 32,768 B
  const unsigned int* cnt = (const unsigned int*)(ws + WS_CNT);
  const unsigned int* entries = (const unsigned int*)(ws + WS_ENT);
  const __bf16* inbf = (const __bf16*)(ws + WS_INBF);
  const __bf16* wt = (const __bf16*)(ws + WS_WT);

  const int b = blockIdx.x;
  const int tid = threadIdx.x;
  const int wave = tid >> 6, lane = tid & 63;
  const int c = lane & 15, q = lane >> 4;
  unsigned char* stage = lds + wave * 8192;
  unsigned char* pmat = stage + 4096;

  // zero this wave's pmat ONCE: b32 stride-1 across lanes = conflict-free
#pragma unroll
  for (int i = 0; i < 16; ++i)
    *(float*)(pmat + i * 256 + lane * 4) = 0.f;

  f32x4 acc[4][4];
#pragma unroll
  for (int rb = 0; rb < 4; ++rb)
#pragma unroll
    for (int nt = 0; nt < 4; ++nt) acc[rb][nt] = (f32x4){0.f, 0.f, 0.f, 0.f};

  for (int kb = wave; kb < K_VOL; kb += 4) {
    unsigned int e0 = cnt[(b << 5) + kb];
    if (e0 == 0) continue;
    if (e0 > CAP) e0 = CAP;

    bf16x8 bfrag[4][2];
#pragma unroll
    for (int nt = 0; nt < 4; ++nt) {
      const __bf16* wrow = wt + ((kb * 64 + nt * 16 + c) << 6);
#pragma unroll
      for (int s = 0; s < 2; ++s)
        bfrag[nt][s] = *(const bf16x8*)(wrow + s * 32 + q * 8);
    }

    const unsigned int* base = entries + (b * K_VOL + kb) * CAP;

    for (unsigned int tb = 0; tb < e0; tb += 32) {
      const unsigned int i0 = tb + c, i1 = tb + 16 + c;
      const unsigned int ent0 = (i0 < e0) ? base[i0] : SENT;
      const unsigned int ent1 = (i1 < e0) ? base[i1] : SENT;

      // invalid entries gather row 0 (their P^T column is all-zero)
      const unsigned int r0 = (ent0 == SENT) ? 0u : (ent0 & 0x1FFFFu);
      const unsigned int r1 = (ent1 == SENT) ? 0u : (ent1 & 0x1FFFFu);
      const __bf16* ar0 = inbf + ((size_t)r0 << 6);
      const __bf16* ar1 = inbf + ((size_t)r1 << 6);
      bf16x8 a00 = *(const bf16x8*)(ar0 + q * 8);
      bf16x8 a01 = *(const bf16x8*)(ar0 + 32 + q * 8);
      bf16x8 a10 = *(const bf16x8*)(ar1 + q * 8);
      bf16x8 a11 = *(const bf16x8*)(ar1 + 32 + q * 8);

      // mark P^T[ol][m]=1 (distinct m => distinct addresses, plain b16)
      int mol0 = -1, mol1 = -1;
      if (q == 0 && ent0 != SENT) mol0 = (int)(ent0 >> 17);
      if (q == 1 && ent1 != SENT) mol1 = (int)(ent1 >> 17);
      if (mol0 >= 0) {
        int m = c;
        *(__bf16*)(pmat + mol0 * 64 + (((m >> 3) ^ (mol0 & 3)) << 4) + (m & 7) * 2) =
            (__bf16)1.0f;
      }
      if (mol1 >= 0) {
        int m = 16 + c;
        *(__bf16*)(pmat + mol1 * 64 + (((m >> 3) ^ (mol1 & 3)) << 4) + (m & 7) * 2) =
            (__bf16)1.0f;
      }

      // C1 = A x W for both 16-entry half-tiles
      f32x4 c1a[4], c1b[4];
#pragma unroll
      for (int nt = 0; nt < 4; ++nt) {
        c1a[nt] = (f32x4){0.f, 0.f, 0.f, 0.f};
        c1b[nt] = (f32x4){0.f, 0.f, 0.f, 0.f};
      }
#pragma unroll
      for (int nt = 0; nt < 4; ++nt) {
        c1a[nt] = __builtin_amdgcn_mfma_f32_16x16x32_bf16(a00, bfrag[nt][0],
                                                          c1a[nt], 0, 0, 0);
        c1a[nt] = __builtin_amdgcn_mfma_f32_16x16x32_bf16(a01, bfrag[nt][1],
                                                          c1a[nt], 0, 0, 0);
        c1b[nt] = __builtin_amdgcn_mfma_f32_16x16x32_bf16(a10, bfrag[nt][0],
                                                          c1b[nt], 0, 0, 0);
        c1b[nt] = __builtin_amdgcn_mfma_f32_16x16x32_bf16(a11, bfrag[nt][1],
                                                          c1b[nt], 0, 0, 0);
      }

      // stage C1 as bf16: [n:64][m:32], 16B-slot XOR swizzle (slot ^= n&3)
#pragma unroll
      for (int nt = 0; nt < 4; ++nt) {
        const int n = nt * 16 + c;
        const int swz = n & 3;
        const int in0 = (q & 1) * 8;
        bf16x4 h0, h1;
#pragma unroll
        for (int r = 0; r < 4; ++r) {
          h0[r] = (__bf16)c1a[nt][r];
          h1[r] = (__bf16)c1b[nt][r];
        }
        *(bf16x4*)(stage + n * 64 + (((q >> 1) ^ swz) << 4) + in0) = h0;
        *(bf16x4*)(stage + n * 64 + (((2 + (q >> 1)) ^ swz) << 4) + in0) = h1;
      }

      // scatter: acc[rb] += P^T rows [16rb,16rb+16) (16x32) x C1 (32x64)
      bf16x8 pa[4];
#pragma unroll
      for (int rb = 0; rb < 4; ++rb)
        pa[rb] = *(const bf16x8*)(pmat + (rb * 16 + c) * 64 + ((q ^ (c & 3)) << 4));
#pragma unroll
      for (int nt = 0; nt < 4; ++nt) {
        const int n = nt * 16 + c;
        const bf16x8 bb = *(const bf16x8*)(stage + n * 64 + ((q ^ (n & 3)) << 4));
#pragma unroll
        for (int rb = 0; rb < 4; ++rb)
          acc[rb][nt] = __builtin_amdgcn_mfma_f32_16x16x32_bf16(
              pa[rb], bb, acc[rb][nt], 0, 0, 0);
      }

      // unmark (restore pmat to all-zero for the next tile/bin)
      if (mol0 >= 0) {
        int m = c;
        *(__bf16*)(pmat + mol0 * 64 + (((m >> 3) ^ (mol0 & 3)) << 4) + (m & 7) * 2) =
            (__bf16)0.0f;
      }
      if (mol1 >= 0) {
        int m = 16 + c;
        *(__bf16*)(pmat + mol1 * 64 + (((m >> 3) ^ (mol1 & 3)) << 4) + (m & 7) * 2) =
            (__bf16)0.0f;
      }
    }
  }

  // ---- cross-wave reduce: 4 partial 64x64 f32 tiles -> wave 0, store ----
  __syncthreads();
  float* bufA = (float*)lds;              // 16 KB
  float* bufB = (float*)(lds + 16384);    // 16 KB

  auto REDST = [&](float* buf) {
#pragma unroll
    for (int rb = 0; rb < 4; ++rb)
#pragma unroll
      for (int nt = 0; nt < 4; ++nt)
#pragma unroll
        for (int r = 0; r < 4; ++r) {
          int row = rb * 16 + q * 4 + r;
          int col = (nt * 16 + c) ^ (q << 2) ^ ((q & 1) << 4);
          buf[row * 64 + col] = acc[rb][nt][r];
        }
  };
  auto REDADD = [&](const float* buf) {
#pragma unroll
    for (int rb = 0; rb < 4; ++rb)
#pragma unroll
      for (int nt = 0; nt < 4; ++nt)
#pragma unroll
        for (int r = 0; r < 4; ++r) {
          int row = rb * 16 + q * 4 + r;
          int col = (nt * 16 + c) ^ (q << 2) ^ ((q & 1) << 4);
          acc[rb][nt][r] += buf[row * 64 + col];
        }
  };

  if (wave == 1) REDST(bufA);
  if (wave == 3) REDST(bufB);
  __syncthreads();
  if (wave == 0) REDADD(bufA);
  if (wave == 2) REDADD(bufB);
  __syncthreads();
  if (wave == 2) REDST(bufA);
  __syncthreads();
  if (wave == 0) {
    REDADD(bufA);
    float bv[4];
#pragma unroll
    for (int nt = 0; nt < 4; ++nt) bv[nt] = bias[nt * 16 + c];
#pragma unroll
    for (int rb = 0; rb < 4; ++rb)
#pragma unroll
      for (int r = 0; r < 4; ++r) {
        const int row = b * RPB + rb * 16 + q * 4 + r;
        if (row < N_POINTS) {
#pragma unroll
          for (int nt = 0; nt < 4; ++nt)
            out[row * CCH + nt * 16 + c] = acc[rb][nt][r] + bv[nt];
        }
      }
  }
}

// ============================ fallback path (original) ============================

__global__ __launch_bounds__(256) void init_out_kernel(
    const float* __restrict__ bias, float* __restrict__ out) {
  int tid = blockIdx.x * blockDim.x + threadIdx.x;
  int c4 = tid & 15;
  float4 b = ((const float4*)bias)[c4];
  ((float4*)out)[tid] = b;
}

__global__ __launch_bounds__(256) void spconv_kernel(
    const float* __restrict__ input, const float* __restrict__ weight,
    const int* __restrict__ in_map, const int* __restrict__ out_map,
    float* __restrict__ out) {
  const int k = blockIdx.y;
  const int lane = threadIdx.x & 63;
  const int wave = threadIdx.x >> 6;
  const int col = lane & 15;
  const int quad = lane >> 4;

  const float* Wk = weight + k * (CCH * CCH);
  bf16x8 bfrag[4][2];
#pragma unroll
  for (int nt = 0; nt < 4; ++nt) {
    int co = nt * 16 + col;
#pragma unroll
    for (int s = 0; s < 2; ++s) {
      int ci0 = s * 32 + quad * 8;
      bf16x8 f;
#pragma unroll
      for (int j = 0; j < 8; ++j) f[j] = (__bf16)Wk[(ci0 + j) * CCH + co];
      bfrag[nt][s] = f;
    }
  }

  const int* im = in_map + k * PAIRS;
  const int* om = out_map + k * PAIRS;

  for (int tile = blockIdx.x * NWAVES + wave; tile < TILES_PER_K;
       tile += BX * NWAVES) {
    const int pbase = tile * 16;
    int rin = im[pbase + col];
    const float* arow = input + rin * CCH;
    bf16x8 afrag[2];
#pragma unroll
    for (int s = 0; s < 2; ++s) {
      const float4 x0 = *(const float4*)(arow + s * 32 + quad * 8);
      const float4 x1 = *(const float4*)(arow + s * 32 + quad * 8 + 4);
      bf16x8 f;
      f[0] = (__bf16)x0.x; f[1] = (__bf16)x0.y;
      f[2] = (__bf16)x0.z; f[3] = (__bf16)x0.w;
      f[4] = (__bf16)x1.x; f[5] = (__bf16)x1.y;
      f[6] = (__bf16)x1.z; f[7] = (__bf16)x1.w;
      afrag[s] = f;
    }

    f32x4 acc[4];
#pragma unroll
    for (int nt = 0; nt < 4; ++nt) acc[nt] = (f32x4){0.f, 0.f, 0.f, 0.f};
#pragma unroll
    for (int nt = 0; nt < 4; ++nt) {
      acc[nt] = __builtin_amdgcn_mfma_f32_16x16x32_bf16(afrag[0], bfrag[nt][0],
                                                        acc[nt], 0, 0, 0);
      acc[nt] = __builtin_amdgcn_mfma_f32_16x16x32_bf16(afrag[1], bfrag[nt][1],
                                                        acc[nt], 0, 0, 0);
    }

    int orow[4];
#pragma unroll
    for (int r = 0; r < 4; ++r) orow[r] = om[pbase + quad * 4 + r];
#pragma unroll
    for (int r = 0; r < 4; ++r) {
      float* op = out + orow[r] * CCH + col;
#pragma unroll
      for (int nt = 0; nt < 4; ++nt) atomicAdd(op + nt * 16, acc[nt][r]);
    }
  }
}

// ============================ launch ============================

extern "C" void kernel_launch(void* const* d_in, const int* in_sizes, int n_in,
                              void* d_out, int out_size, void* d_ws,
                              size_t ws_size, hipStream_t stream) {
  const float* input = (const float*)d_in[0];
  const float* weight = (const float*)d_in[1];
  const float* bias = (const float*)d_in[2];
  const int* in_map = (const int*)d_in[3];
  const int* out_map = (const int*)d_in[4];
  float* out = (float*)d_out;

  if (d_ws != nullptr && ws_size >= (size_t)WS_NEED) {
    unsigned char* ws = (unsigned char*)d_ws;
    hipMemsetAsync(ws + WS_CNT, 0, NBUCKETS * CNTSTRIDE * 4, stream);
    prep_fill_kernel<<<PREP_BLKS + FILL_BLKS, 256, 0, stream>>>(
        input, weight, in_map, out_map, ws);
    spconv_main_kernel<<<NBUCKETS, 256, 0, stream>>>(bias, ws, out);
  } else {
    init_out_kernel<<<(N_POINTS * 16) / 256, 256, 0, stream>>>(bias, out);
    dim3 grid(BX, K_VOL);
    spconv_kernel<<<grid, 256, 0, stream>>>(input, weight, in_map, out_map, out);
  }
}

// Round 11
// 265.716 us; speedup vs baseline: 2.4350x; 1.0801x over previous
//
#include <hip/hip_runtime.h>
#include <hip/hip_bf16.h>

#define N_POINTS 100000
#define K_VOL 27
#define PAIRS 60000
#define CCH 64                       // C_IN == C_OUT == 64
#define TILES_PER_K (PAIRS / 16)     // fallback path
#define BX 64                        // fallback path
#define NWAVES 4                     // fallback path

#define RPB 64                                     // rows per output bucket
#define NBUCKETS ((N_POINTS + RPB - 1) / RPB)      // 1563
#define NBINS (NBUCKETS * K_VOL)                   // 42201
#define CAP 96                                     // bin capacity (lambda=38.4)
#define SENT 0xFFFFFFFFu
#define CNTSTRIDE 32                               // counters padded to 128B/bucket

#define PREP_BLKS 6250                             // 1.6M threads for input cvt
#define FILL_BLKS (K_VOL * 64)                     // 1728: per k, 8 slices x 8 subs
#define PSUB (PAIRS / 8)                           // 7500 pairs per sub-range

// workspace layout (bytes)
#define WS_ENT 0
#define WS_CNT (NBINS * CAP * 4)                   // 16,205,184 (128B-aligned)
#define WS_INBF (WS_CNT + NBUCKETS * CNTSTRIDE * 4) // 16,405,248
#define WS_WT (WS_INBF + N_POINTS * CCH * 2)       // 29,205,248
#define WS_NEED (WS_WT + K_VOL * CCH * CCH * 2)    // 29,426,432 (~28.1 MiB)

typedef __bf16 bf16x8 __attribute__((ext_vector_type(8)));
typedef __bf16 bf16x4 __attribute__((ext_vector_type(4)));
typedef float f32x4 __attribute__((ext_vector_type(4)));

// ============================ new path ============================

// Fused prep + XCD-local fill (counters pre-zeroed by hipMemsetAsync).
// See R10 notes: slice = bucket&7 pinned to one XCD via round-robin block ids
// -> bin counter lines never bounce across XCDs (R10: total 317->287us).
// entry = in_row (17b) | out_local (6b) << 17
__global__ __launch_bounds__(256) void prep_fill_kernel(
    const float* __restrict__ input, const float* __restrict__ weight,
    const int* __restrict__ in_map, const int* __restrict__ out_map,
    unsigned char* __restrict__ ws) {
  const int bid = blockIdx.x;
  if (bid < PREP_BLKS) {
    int t = bid * 256 + threadIdx.x;  // exactly N*CCH/4 = 1,600,000 threads
    float4 v = ((const float4*)input)[t];
    bf16x4 o;
    o[0] = (__bf16)v.x; o[1] = (__bf16)v.y; o[2] = (__bf16)v.z; o[3] = (__bf16)v.w;
    *(bf16x4*)(ws + WS_INBF + (size_t)t * 8) = o;
    if (t < K_VOL * CCH * CCH) {             // 110592
      int k = t >> 12;
      int r = t & 4095;
      int ci = r >> 6, co = r & 63;
      *(__bf16*)(ws + WS_WT + (size_t)(((k * 64 + co) << 6) + ci) * 2) =
          (__bf16)weight[t];
    }
  } else {
    const int f = bid - PREP_BLKS;           // [0, 1728)
    const int k = f >> 6;
    const int bx = f & 63;
    const int slice = bx & 7;
    const int sub = bx >> 3;
    const int pbeg = sub * PSUB, pend = pbeg + PSUB;
    const int* omp_ = out_map + k * PAIRS;
    const int* imp_ = in_map + k * PAIRS;
    unsigned int* cntp = (unsigned int*)(ws + WS_CNT);
    unsigned int* entp = (unsigned int*)(ws + WS_ENT);
    for (int p = pbeg + (int)threadIdx.x * 4; p < pend; p += 1024) {
      int4 om4 = *(const int4*)(omp_ + p);
      int4 im4 = *(const int4*)(imp_ + p);
      int oms[4] = {om4.x, om4.y, om4.z, om4.w};
      int ims[4] = {im4.x, im4.y, im4.z, im4.w};
#pragma unroll
      for (int j = 0; j < 4; ++j) {
        int bkt = oms[j] >> 6;
        if ((bkt & 7) != slice) continue;
        unsigned int pos = atomicAdd(cntp + (bkt << 5) + k, 1u);
        if (pos < CAP)
          entp[(bkt * K_VOL + k) * CAP + pos] =
              (unsigned int)ims[j] | ((unsigned int)(oms[j] & 63) << 17);
      }
    }
  }
}

// One block per 64-row bucket; per-wave SOFTWARE-PIPELINED bin loop:
// at bin j, issue bin j+4's cnt+entry loads; after tile0 compute, mask and
// issue j+4's A-row gathers (tile1 compute hides them); reload bfrag for
// j+4 after its last use. Tile body (mark pmat -> C1 MFMA -> bf16 stage ->
// scatter MFMA -> unmark) is byte-identical to the verified R10 kernel.
// Speculative entry loads stay inside the fixed-CAP region; garbage slots
// are masked to SENT BEFORE any row index is formed (no OOB gathers).
// NOTE: no min-waves bound -- ~230 unified regs (incl 64 AGPR acc) ->
// 2 waves/SIMD; capping lower spills the accumulators (R8: 4.6x slowdown).
__global__ __launch_bounds__(256) void spconv_main_kernel(
    const float* __restrict__ bias, const unsigned char* __restrict__ ws,
    float* __restrict__ out) {
  __shared__ __align__(16) unsigned char lds[4 * 8192];   // 32,768 B
  const unsigned int* cnt = (const unsigned int*)(ws + WS_CNT);
  const unsigned int* entries = (const unsigned int*)(ws + WS_ENT);
  const __bf16* inbf = (const __bf16*)(ws + WS_INBF);
  const __bf16* wt = (const __bf16*)(ws + WS_WT);

  const int b = blockIdx.x;
  const int tid = threadIdx.x;
  const int wave = tid >> 6, lane = tid & 63;
  const int c = lane & 15, q = lane >> 4;
  unsigned char* stage = lds + wave * 8192;
  unsigned char* pmat = stage + 4096;

  // zero this wave's pmat ONCE: b32 stride-1 across lanes = conflict-free
#pragma unroll
  for (int i = 0; i < 16; ++i)
    *(float*)(pmat + i * 256 + lane * 4) = 0.f;

  f32x4 acc[4][4];
#pragma unroll
  for (int rb = 0; rb < 4; ++rb)
#pragma unroll
    for (int nt = 0; nt < 4; ++nt) acc[rb][nt] = (f32x4){0.f, 0.f, 0.f, 0.f};

  bf16x8 bfA0[4], bfA1[4];   // current bin's B fragments

  // gather both halves of one input row (SENT -> row 0, harmless: its P^T
  // column is all-zero)
  auto grow = [&](unsigned v, bf16x8& x0, bf16x8& x1) {
    unsigned r = (v == SENT) ? 0u : (v & 0x1FFFFu);
    const __bf16* ar = inbf + ((size_t)r << 6);
    x0 = *(const bf16x8*)(ar + q * 8);
    x1 = *(const bf16x8*)(ar + 32 + q * 8);
  };

  // one 32-entry tile: mark -> C1 -> stage -> scatter -> unmark (R10 body)
  auto do_tile = [&](unsigned entL, unsigned entH, bf16x8 aL0, bf16x8 aL1,
                     bf16x8 aH0, bf16x8 aH1) {
    int mol0 = -1, mol1 = -1;
    if (q == 0 && entL != SENT) mol0 = (int)(entL >> 17);
    if (q == 1 && entH != SENT) mol1 = (int)(entH >> 17);
    if (mol0 >= 0) {
      int m = c;
      *(__bf16*)(pmat + mol0 * 64 + (((m >> 3) ^ (mol0 & 3)) << 4) + (m & 7) * 2) =
          (__bf16)1.0f;
    }
    if (mol1 >= 0) {
      int m = 16 + c;
      *(__bf16*)(pmat + mol1 * 64 + (((m >> 3) ^ (mol1 & 3)) << 4) + (m & 7) * 2) =
          (__bf16)1.0f;
    }

    f32x4 c1a[4], c1b[4];
#pragma unroll
    for (int nt = 0; nt < 4; ++nt) {
      c1a[nt] = (f32x4){0.f, 0.f, 0.f, 0.f};
      c1b[nt] = (f32x4){0.f, 0.f, 0.f, 0.f};
    }
#pragma unroll
    for (int nt = 0; nt < 4; ++nt) {
      c1a[nt] = __builtin_amdgcn_mfma_f32_16x16x32_bf16(aL0, bfA0[nt], c1a[nt],
                                                        0, 0, 0);
      c1a[nt] = __builtin_amdgcn_mfma_f32_16x16x32_bf16(aL1, bfA1[nt], c1a[nt],
                                                        0, 0, 0);
      c1b[nt] = __builtin_amdgcn_mfma_f32_16x16x32_bf16(aH0, bfA0[nt], c1b[nt],
                                                        0, 0, 0);
      c1b[nt] = __builtin_amdgcn_mfma_f32_16x16x32_bf16(aH1, bfA1[nt], c1b[nt],
                                                        0, 0, 0);
    }

    // stage C1 as bf16: [n:64][m:32], 16B-slot XOR swizzle (slot ^= n&3)
#pragma unroll
    for (int nt = 0; nt < 4; ++nt) {
      const int n = nt * 16 + c;
      const int swz = n & 3;
      const int in0 = (q & 1) * 8;
      bf16x4 h0, h1;
#pragma unroll
      for (int r = 0; r < 4; ++r) {
        h0[r] = (__bf16)c1a[nt][r];
        h1[r] = (__bf16)c1b[nt][r];
      }
      *(bf16x4*)(stage + n * 64 + (((q >> 1) ^ swz) << 4) + in0) = h0;
      *(bf16x4*)(stage + n * 64 + (((2 + (q >> 1)) ^ swz) << 4) + in0) = h1;
    }

    // scatter: acc[rb] += P^T rows [16rb,16rb+16) (16x32) x C1 (32x64)
    bf16x8 pfrag[4];
#pragma unroll
    for (int rb = 0; rb < 4; ++rb)
      pfrag[rb] = *(const bf16x8*)(pmat + (rb * 16 + c) * 64 + ((q ^ (c & 3)) << 4));
#pragma unroll
    for (int nt = 0; nt < 4; ++nt) {
      const int n = nt * 16 + c;
      const bf16x8 bb = *(const bf16x8*)(stage + n * 64 + ((q ^ (n & 3)) << 4));
#pragma unroll
      for (int rb = 0; rb < 4; ++rb)
        acc[rb][nt] = __builtin_amdgcn_mfma_f32_16x16x32_bf16(pfrag[rb], bb,
                                                             acc[rb][nt], 0, 0, 0);
    }

    // unmark (restore pmat to all-zero)
    if (mol0 >= 0) {
      int m = c;
      *(__bf16*)(pmat + mol0 * 64 + (((m >> 3) ^ (mol0 & 3)) << 4) + (m & 7) * 2) =
          (__bf16)0.0f;
    }
    if (mol1 >= 0) {
      int m = 16 + c;
      *(__bf16*)(pmat + mol1 * 64 + (((m >> 3) ^ (mol1 & 3)) << 4) + (m & 7) * 2) =
          (__bf16)0.0f;
    }
  };

  // ---- prologue: prefetch first bin (j = wave) ----------------------------
  int j = wave;
  unsigned ecp, v0, v1, v2, v3;
  bf16x8 pa00, pa01, pa10, pa11, pa20, pa21, pa30, pa31;
  {
    unsigned cn = cnt[(b << 5) + j];
    const unsigned* bp = entries + (size_t)(b * K_VOL + j) * CAP;
    unsigned g0 = bp[c], g1 = bp[16 + c], g2 = bp[32 + c], g3 = bp[48 + c];
    ecp = cn > CAP ? (unsigned)CAP : cn;
    v0 = ((unsigned)c < ecp) ? g0 : SENT;
    v1 = ((unsigned)(16 + c) < ecp) ? g1 : SENT;
    v2 = ((unsigned)(32 + c) < ecp) ? g2 : SENT;
    v3 = ((unsigned)(48 + c) < ecp) ? g3 : SENT;
    grow(v0, pa00, pa01); grow(v1, pa10, pa11);
    grow(v2, pa20, pa21); grow(v3, pa30, pa31);
  }
#pragma unroll
  for (int nt = 0; nt < 4; ++nt) {
    const __bf16* wrow = wt + ((j * 64 + nt * 16 + c) << 6);
    bfA0[nt] = *(const bf16x8*)(wrow + q * 8);
    bfA1[nt] = *(const bf16x8*)(wrow + 32 + q * 8);
  }

  // ---- pipelined bin loop -------------------------------------------------
  while (j < K_VOL) {
    const int jn = j + 4;
    const bool hasn = jn < K_VOL;
    const unsigned ec = ecp;
    const unsigned w0 = v0, w1 = v1, w2 = v2, w3 = v3;
    const bf16x8 qa00 = pa00, qa01 = pa01, qa10 = pa10, qa11 = pa11;
    const bf16x8 qa20 = pa20, qa21 = pa21, qa30 = pa30, qa31 = pa31;

    // issue next bin's cnt + entry loads NOW (latency hides under tile0)
    unsigned ncn = 0, g0 = SENT, g1 = SENT, g2 = SENT, g3 = SENT;
    if (hasn) {
      ncn = cnt[(b << 5) + jn];
      const unsigned* bpn = entries + (size_t)(b * K_VOL + jn) * CAP;
      g0 = bpn[c]; g1 = bpn[16 + c]; g2 = bpn[32 + c]; g3 = bpn[48 + c];
    }

    if (ec) do_tile(w0, w1, qa00, qa01, qa10, qa11);

    // mask + issue next bin's A gathers (tile1 compute hides them)
    if (hasn) {
      ecp = ncn > CAP ? (unsigned)CAP : ncn;
      v0 = ((unsigned)c < ecp) ? g0 : SENT;
      v1 = ((unsigned)(16 + c) < ecp) ? g1 : SENT;
      v2 = ((unsigned)(32 + c) < ecp) ? g2 : SENT;
      v3 = ((unsigned)(48 + c) < ecp) ? g3 : SENT;
      grow(v0, pa00, pa01); grow(v1, pa10, pa11);
      grow(v2, pa20, pa21); grow(v3, pa30, pa31);
    }

    if (ec > 32) do_tile(w2, w3, qa20, qa21, qa30, qa31);

    // rare overflow tiles (P(n>64) ~ 1e-4 per bin): serial path
    for (unsigned tb = 64; tb < ec; tb += 32) {
      const unsigned* base = entries + (size_t)(b * K_VOL + j) * CAP;
      unsigned i0 = tb + c, i1 = tb + 16 + c;
      unsigned e0 = (i0 < ec) ? base[i0] : SENT;
      unsigned e1 = (i1 < ec) ? base[i1] : SENT;
      bf16x8 x00, x01, x10, x11;
      grow(e0, x00, x01);
      grow(e1, x10, x11);
      do_tile(e0, e1, x00, x01, x10, x11);
    }

    // reload bfrag for next bin AFTER its last use this bin
    if (hasn) {
#pragma unroll
      for (int nt = 0; nt < 4; ++nt) {
        const __bf16* wrow = wt + ((jn * 64 + nt * 16 + c) << 6);
        bfA0[nt] = *(const bf16x8*)(wrow + q * 8);
        bfA1[nt] = *(const bf16x8*)(wrow + 32 + q * 8);
      }
    }
    j = jn;
  }

  // ---- cross-wave reduce: 4 partial 64x64 f32 tiles -> wave 0, store ----
  __syncthreads();
  float* bufA = (float*)lds;              // 16 KB
  float* bufB = (float*)(lds + 16384);    // 16 KB

  auto REDST = [&](float* buf) {
#pragma unroll
    for (int rb = 0; rb < 4; ++rb)
#pragma unroll
      for (int nt = 0; nt < 4; ++nt)
#pragma unroll
        for (int r = 0; r < 4; ++r) {
          int row = rb * 16 + q * 4 + r;
          int col = (nt * 16 + c) ^ (q << 2) ^ ((q & 1) << 4);
          buf[row * 64 + col] = acc[rb][nt][r];
        }
  };
  auto REDADD = [&](const float* buf) {
#pragma unroll
    for (int rb = 0; rb < 4; ++rb)
#pragma unroll
      for (int nt = 0; nt < 4; ++nt)
#pragma unroll
        for (int r = 0; r < 4; ++r) {
          int row = rb * 16 + q * 4 + r;
          int col = (nt * 16 + c) ^ (q << 2) ^ ((q & 1) << 4);
          acc[rb][nt][r] += buf[row * 64 + col];
        }
  };

  if (wave == 1) REDST(bufA);
  if (wave == 3) REDST(bufB);
  __syncthreads();
  if (wave == 0) REDADD(bufA);
  if (wave == 2) REDADD(bufB);
  __syncthreads();
  if (wave == 2) REDST(bufA);
  __syncthreads();
  if (wave == 0) {
    REDADD(bufA);
    float bv[4];
#pragma unroll
    for (int nt = 0; nt < 4; ++nt) bv[nt] = bias[nt * 16 + c];
#pragma unroll
    for (int rb = 0; rb < 4; ++rb)
#pragma unroll
      for (int r = 0; r < 4; ++r) {
        const int row = b * RPB + rb * 16 + q * 4 + r;
        if (row < N_POINTS) {
#pragma unroll
          for (int nt = 0; nt < 4; ++nt)
            out[row * CCH + nt * 16 + c] = acc[rb][nt][r] + bv[nt];
        }
      }
  }
}

// ============================ fallback path (original) ============================

__global__ __launch_bounds__(256) void init_out_kernel(
    const float* __restrict__ bias, float* __restrict__ out) {
  int tid = blockIdx.x * blockDim.x + threadIdx.x;
  int c4 = tid & 15;
  float4 b = ((const float4*)bias)[c4];
  ((float4*)out)[tid] = b;
}

__global__ __launch_bounds__(256) void spconv_kernel(
    const float* __restrict__ input, const float* __restrict__ weight,
    const int* __restrict__ in_map, const int* __restrict__ out_map,
    float* __restrict__ out) {
  const int k = blockIdx.y;
  const int lane = threadIdx.x & 63;
  const int wave = threadIdx.x >> 6;
  const int col = lane & 15;
  const int quad = lane >> 4;

  const float* Wk = weight + k * (CCH * CCH);
  bf16x8 bfrag[4][2];
#pragma unroll
  for (int nt = 0; nt < 4; ++nt) {
    int co = nt * 16 + col;
#pragma unroll
    for (int s = 0; s < 2; ++s) {
      int ci0 = s * 32 + quad * 8;
      bf16x8 f;
#pragma unroll
      for (int j = 0; j < 8; ++j) f[j] = (__bf16)Wk[(ci0 + j) * CCH + co];
      bfrag[nt][s] = f;
    }
  }

  const int* im = in_map + k * PAIRS;
  const int* om = out_map + k * PAIRS;

  for (int tile = blockIdx.x * NWAVES + wave; tile < TILES_PER_K;
       tile += BX * NWAVES) {
    const int pbase = tile * 16;
    int rin = im[pbase + col];
    const float* arow = input + rin * CCH;
    bf16x8 afrag[2];
#pragma unroll
    for (int s = 0; s < 2; ++s) {
      const float4 x0 = *(const float4*)(arow + s * 32 + quad * 8);
      const float4 x1 = *(const float4*)(arow + s * 32 + quad * 8 + 4);
      bf16x8 f;
      f[0] = (__bf16)x0.x; f[1] = (__bf16)x0.y;
      f[2] = (__bf16)x0.z; f[3] = (__bf16)x0.w;
      f[4] = (__bf16)x1.x; f[5] = (__bf16)x1.y;
      f[6] = (__bf16)x1.z; f[7] = (__bf16)x1.w;
      afrag[s] = f;
    }

    f32x4 acc[4];
#pragma unroll
    for (int nt = 0; nt < 4; ++nt) acc[nt] = (f32x4){0.f, 0.f, 0.f, 0.f};
#pragma unroll
    for (int nt = 0; nt < 4; ++nt) {
      acc[nt] = __builtin_amdgcn_mfma_f32_16x16x32_bf16(afrag[0], bfrag[nt][0],
                                                        acc[nt], 0, 0, 0);
      acc[nt] = __builtin_amdgcn_mfma_f32_16x16x32_bf16(afrag[1], bfrag[nt][1],
                                                        acc[nt], 0, 0, 0);
    }

    int orow[4];
#pragma unroll
    for (int r = 0; r < 4; ++r) orow[r] = om[pbase + quad * 4 + r];
#pragma unroll
    for (int r = 0; r < 4; ++r) {
      float* op = out + orow[r] * CCH + col;
#pragma unroll
      for (int nt = 0; nt < 4; ++nt) atomicAdd(op + nt * 16, acc[nt][r]);
    }
  }
}

// ============================ launch ============================

extern "C" void kernel_launch(void* const* d_in, const int* in_sizes, int n_in,
                              void* d_out, int out_size, void* d_ws,
                              size_t ws_size, hipStream_t stream) {
  const float* input = (const float*)d_in[0];
  const float* weight = (const float*)d_in[1];
  const float* bias = (const float*)d_in[2];
  const int* in_map = (const int*)d_in[3];
  const int* out_map = (const int*)d_in[4];
  float* out = (float*)d_out;

  if (d_ws != nullptr && ws_size >= (size_t)WS_NEED) {
    unsigned char* ws = (unsigned char*)d_ws;
    hipMemsetAsync(ws + WS_CNT, 0, NBUCKETS * CNTSTRIDE * 4, stream);
    prep_fill_kernel<<<PREP_BLKS + FILL_BLKS, 256, 0, stream>>>(
        input, weight, in_map, out_map, ws);
    spconv_main_kernel<<<NBUCKETS, 256, 0, stream>>>(bias, ws, out);
  } else {
    init_out_kernel<<<(N_POINTS * 16) / 256, 256, 0, stream>>>(bias, out);
    dim3 grid(BX, K_VOL);
    spconv_kernel<<<grid, 256, 0, stream>>>(input, weight, in_map, out_map, out);
  }
}

// Round 13
// 227.237 us; speedup vs baseline: 2.8474x; 1.1693x over previous
//
#include <hip/hip_runtime.h>
#include <hip/hip_bf16.h>

#define N_POINTS 100000
#define K_VOL 27
#define PAIRS 60000
#define CCH 64                       // C_IN == C_OUT == 64
#define TILES_PER_K (PAIRS / 16)     // fallback path
#define BX 64                        // fallback path
#define NWAVES 4                     // fallback path

#define RPB 64                                     // rows per output bucket
#define NBUCKETS ((N_POINTS + RPB - 1) / RPB)      // 1563
#define NBINS (NBUCKETS * K_VOL)                   // 42201
#define CAP 96                                     // bin capacity (lambda=38.4)
#define SENT 0xFFFFFFFFu
#define CNTSTRIDE 32                               // counters padded to 128B/bucket

#define PREP_BLKS 6250                             // 1.6M threads for input cvt
#define FILL_BLKS (K_VOL * 64)                     // 1728: per k, 8 slices x 8 subs
#define PSUB (PAIRS / 8)                           // 7500 pairs per sub-range
#define NLB 200                                    // local buckets per slice (<=196)

// workspace layout (bytes)
#define WS_ENT 0
#define WS_CNT (NBINS * CAP * 4)                   // 16,205,184 (128B-aligned)
#define WS_INBF (WS_CNT + NBUCKETS * CNTSTRIDE * 4) // 16,405,248
#define WS_WT (WS_INBF + N_POINTS * CCH * 2)       // 29,205,248
#define WS_NEED (WS_WT + K_VOL * CCH * CCH * 2)    // 29,426,432 (~28.1 MiB)

typedef __bf16 bf16x8 __attribute__((ext_vector_type(8)));
typedef __bf16 bf16x4 __attribute__((ext_vector_type(4)));
typedef float f32x4 __attribute__((ext_vector_type(4)));

// ============================ new path ============================

// Fused prep + XCD-local fill (counters pre-zeroed by hipMemsetAsync).
// Fill (R12): per block, two-pass LDS-count + cell-reserve:
//   pass1 counts matching pairs into LDS cells (bkt>>3); one global
//   atomicAdd per NONZERO cell reserves a contiguous range in the bin
//   (330K global atomics total vs 1.62M per-entry); pass2 re-reads the
//   L3-resident maps and writes entries at LDS-cursored positions --
//   ~5-entry coalesced bursts instead of random 4B scatters.
// Slicing (bucket&7 pinned to one XCD via round-robin block ids) retained
// from R10 (+30us). entry = in_row (17b) | out_local (6b) << 17
__global__ __launch_bounds__(256) void prep_fill_kernel(
    const float* __restrict__ input, const float* __restrict__ weight,
    const int* __restrict__ in_map, const int* __restrict__ out_map,
    unsigned char* __restrict__ ws) {
  const int bid = blockIdx.x;
  if (bid < PREP_BLKS) {
    int t = bid * 256 + threadIdx.x;  // exactly N*CCH/4 = 1,600,000 threads
    float4 v = ((const float4*)input)[t];
    bf16x4 o;
    o[0] = (__bf16)v.x; o[1] = (__bf16)v.y; o[2] = (__bf16)v.z; o[3] = (__bf16)v.w;
    *(bf16x4*)(ws + WS_INBF + (size_t)t * 8) = o;
    if (t < K_VOL * CCH * CCH) {             // 110592
      int k = t >> 12;
      int r = t & 4095;
      int ci = r >> 6, co = r & 63;
      *(__bf16*)(ws + WS_WT + (size_t)(((k * 64 + co) << 6) + ci) * 2) =
          (__bf16)weight[t];
    }
  } else {
    __shared__ unsigned int lcnt[NLB];
    __shared__ unsigned int lcur[NLB];
    const int f = bid - PREP_BLKS;           // [0, 1728)
    const int k = f >> 6;
    const int bx = f & 63;
    const int slice = bx & 7;
    const int sub = bx >> 3;
    const int pbeg = sub * PSUB, pend = pbeg + PSUB;
    const int* omp_ = out_map + k * PAIRS;
    const int* imp_ = in_map + k * PAIRS;
    unsigned int* cntp = (unsigned int*)(ws + WS_CNT);
    unsigned int* entp = (unsigned int*)(ws + WS_ENT);

    for (int i = threadIdx.x; i < NLB; i += 256) lcnt[i] = 0;
    __syncthreads();

    // pass 1: count matching pairs per local bucket (bkt = lb*8 + slice)
    for (int p = pbeg + (int)threadIdx.x * 4; p < pend; p += 1024) {
      int4 om4 = *(const int4*)(omp_ + p);
      int oms[4] = {om4.x, om4.y, om4.z, om4.w};
#pragma unroll
      for (int j = 0; j < 4; ++j) {
        int bkt = oms[j] >> 6;
        if ((bkt & 7) == slice) atomicAdd(&lcnt[bkt >> 3], 1u);
      }
    }
    __syncthreads();

    // reserve: ONE global atomic per nonzero cell; cursor = global base
    for (int lb = threadIdx.x; lb < NLB; lb += 256) {
      unsigned n = lcnt[lb];
      if (n) {
        int bkt = (lb << 3) | slice;         // always < NBUCKETS (om<100000)
        lcur[lb] = atomicAdd(cntp + (bkt << 5) + k, n);
      }
    }
    __syncthreads();

    // pass 2: write entries at LDS-cursored global positions
    for (int p = pbeg + (int)threadIdx.x * 4; p < pend; p += 1024) {
      int4 om4 = *(const int4*)(omp_ + p);
      int4 im4 = *(const int4*)(imp_ + p);
      int oms[4] = {om4.x, om4.y, om4.z, om4.w};
      int ims[4] = {im4.x, im4.y, im4.z, im4.w};
#pragma unroll
      for (int j = 0; j < 4; ++j) {
        int bkt = oms[j] >> 6;
        if ((bkt & 7) != slice) continue;
        unsigned pos = atomicAdd(&lcur[bkt >> 3], 1u);
        if (pos < CAP)
          entp[(bkt * K_VOL + k) * CAP + pos] =
              (unsigned)ims[j] | ((unsigned)(oms[j] & 63) << 17);
      }
    }
  }
}

// One block per 64-row bucket; per-wave 2-DEEP software-pipelined bin loop:
// entries/cnt prefetched TWO bins ahead (j+8), so bin j+4's A-row gathers
// are issued at the TOP of bin j's compute (full ~600cy cover, vs one tile
// in R11). Tile body (mark pmat -> C1 MFMA -> bf16 stage -> scatter MFMA ->
// unmark) is byte-identical to the verified R10/R11 kernel.
// NOTE: no min-waves bound -- capping unified regs spills the 64-AGPR acc
// (R8: 4.6x slowdown). Spill canary: WRITE_SIZE must stay 25MB.
__global__ __launch_bounds__(256) void spconv_main_kernel(
    const float* __restrict__ bias, const unsigned char* __restrict__ ws,
    float* __restrict__ out) {
  __shared__ __align__(16) unsigned char lds[4 * 8192];   // 32,768 B
  const unsigned int* cnt = (const unsigned int*)(ws + WS_CNT);
  const unsigned int* entries = (const unsigned int*)(ws + WS_ENT);
  const __bf16* inbf = (const __bf16*)(ws + WS_INBF);
  const __bf16* wt = (const __bf16*)(ws + WS_WT);

  const int b = blockIdx.x;
  const int tid = threadIdx.x;
  const int wave = tid >> 6, lane = tid & 63;
  const int c = lane & 15, q = lane >> 4;
  unsigned char* stage = lds + wave * 8192;
  unsigned char* pmat = stage + 4096;

  // zero this wave's pmat ONCE: b32 stride-1 across lanes = conflict-free
#pragma unroll
  for (int i = 0; i < 16; ++i)
    *(float*)(pmat + i * 256 + lane * 4) = 0.f;

  f32x4 acc[4][4];
#pragma unroll
  for (int rb = 0; rb < 4; ++rb)
#pragma unroll
    for (int nt = 0; nt < 4; ++nt) acc[rb][nt] = (f32x4){0.f, 0.f, 0.f, 0.f};

  bf16x8 bfA0[4], bfA1[4];   // current bin's B fragments

  auto grow = [&](unsigned v, bf16x8& x0, bf16x8& x1) {
    unsigned r = (v == SENT) ? 0u : (v & 0x1FFFFu);
    const __bf16* ar = inbf + ((size_t)r << 6);
    x0 = *(const bf16x8*)(ar + q * 8);
    x1 = *(const bf16x8*)(ar + 32 + q * 8);
  };

  // one 32-entry tile: mark -> C1 -> stage -> scatter -> unmark (R10 body)
  auto do_tile = [&](unsigned entL, unsigned entH, bf16x8 aL0, bf16x8 aL1,
                     bf16x8 aH0, bf16x8 aH1) {
    int mol0 = -1, mol1 = -1;
    if (q == 0 && entL != SENT) mol0 = (int)(entL >> 17);
    if (q == 1 && entH != SENT) mol1 = (int)(entH >> 17);
    if (mol0 >= 0) {
      int m = c;
      *(__bf16*)(pmat + mol0 * 64 + (((m >> 3) ^ (mol0 & 3)) << 4) + (m & 7) * 2) =
          (__bf16)1.0f;
    }
    if (mol1 >= 0) {
      int m = 16 + c;
      *(__bf16*)(pmat + mol1 * 64 + (((m >> 3) ^ (mol1 & 3)) << 4) + (m & 7) * 2) =
          (__bf16)1.0f;
    }

    f32x4 c1a[4], c1b[4];
#pragma unroll
    for (int nt = 0; nt < 4; ++nt) {
      c1a[nt] = (f32x4){0.f, 0.f, 0.f, 0.f};
      c1b[nt] = (f32x4){0.f, 0.f, 0.f, 0.f};
    }
#pragma unroll
    for (int nt = 0; nt < 4; ++nt) {
      c1a[nt] = __builtin_amdgcn_mfma_f32_16x16x32_bf16(aL0, bfA0[nt], c1a[nt],
                                                        0, 0, 0);
      c1a[nt] = __builtin_amdgcn_mfma_f32_16x16x32_bf16(aL1, bfA1[nt], c1a[nt],
                                                        0, 0, 0);
      c1b[nt] = __builtin_amdgcn_mfma_f32_16x16x32_bf16(aH0, bfA0[nt], c1b[nt],
                                                        0, 0, 0);
      c1b[nt] = __builtin_amdgcn_mfma_f32_16x16x32_bf16(aH1, bfA1[nt], c1b[nt],
                                                        0, 0, 0);
    }

#pragma unroll
    for (int nt = 0; nt < 4; ++nt) {
      const int n = nt * 16 + c;
      const int swz = n & 3;
      const int in0 = (q & 1) * 8;
      bf16x4 h0, h1;
#pragma unroll
      for (int r = 0; r < 4; ++r) {
        h0[r] = (__bf16)c1a[nt][r];
        h1[r] = (__bf16)c1b[nt][r];
      }
      *(bf16x4*)(stage + n * 64 + (((q >> 1) ^ swz) << 4) + in0) = h0;
      *(bf16x4*)(stage + n * 64 + (((2 + (q >> 1)) ^ swz) << 4) + in0) = h1;
    }

    bf16x8 pfrag[4];
#pragma unroll
    for (int rb = 0; rb < 4; ++rb)
      pfrag[rb] = *(const bf16x8*)(pmat + (rb * 16 + c) * 64 + ((q ^ (c & 3)) << 4));
#pragma unroll
    for (int nt = 0; nt < 4; ++nt) {
      const int n = nt * 16 + c;
      const bf16x8 bb = *(const bf16x8*)(stage + n * 64 + ((q ^ (n & 3)) << 4));
#pragma unroll
      for (int rb = 0; rb < 4; ++rb)
        acc[rb][nt] = __builtin_amdgcn_mfma_f32_16x16x32_bf16(pfrag[rb], bb,
                                                             acc[rb][nt], 0, 0, 0);
    }

    if (mol0 >= 0) {
      int m = c;
      *(__bf16*)(pmat + mol0 * 64 + (((m >> 3) ^ (mol0 & 3)) << 4) + (m & 7) * 2) =
          (__bf16)0.0f;
    }
    if (mol1 >= 0) {
      int m = 16 + c;
      *(__bf16*)(pmat + mol1 * 64 + (((m >> 3) ^ (mol1 & 3)) << 4) + (m & 7) * 2) =
          (__bf16)0.0f;
    }
  };

  // ---- prologue: bin j ready; bin j+4 entries masked ----------------------
  int j = wave;
  unsigned ec, w0, w1, w2, w3;                                 // bin j
  bf16x8 qa00, qa01, qa10, qa11, qa20, qa21, qa30, qa31;
  unsigned ecn, x0, x1, x2, x3;                                // bin j+4
  {
    unsigned cn0 = cnt[(b << 5) + j];
    const unsigned* bp0 = entries + (size_t)(b * K_VOL + j) * CAP;
    unsigned a0 = bp0[c], a1 = bp0[16 + c], a2 = bp0[32 + c], a3 = bp0[48 + c];
    unsigned cn1 = 0, b0 = SENT, b1 = SENT, b2 = SENT, b3 = SENT;
    if (j + 4 < K_VOL) {
      cn1 = cnt[(b << 5) + j + 4];
      const unsigned* bp1 = entries + (size_t)(b * K_VOL + j + 4) * CAP;
      b0 = bp1[c]; b1 = bp1[16 + c]; b2 = bp1[32 + c]; b3 = bp1[48 + c];
    }
    ec = cn0 > CAP ? (unsigned)CAP : cn0;
    w0 = ((unsigned)c < ec) ? a0 : SENT;
    w1 = ((unsigned)(16 + c) < ec) ? a1 : SENT;
    w2 = ((unsigned)(32 + c) < ec) ? a2 : SENT;
    w3 = ((unsigned)(48 + c) < ec) ? a3 : SENT;
    grow(w0, qa00, qa01); grow(w1, qa10, qa11);
    grow(w2, qa20, qa21); grow(w3, qa30, qa31);
    ecn = cn1 > CAP ? (unsigned)CAP : cn1;
    x0 = ((unsigned)c < ecn) ? b0 : SENT;
    x1 = ((unsigned)(16 + c) < ecn) ? b1 : SENT;
    x2 = ((unsigned)(32 + c) < ecn) ? b2 : SENT;
    x3 = ((unsigned)(48 + c) < ecn) ? b3 : SENT;
  }
#pragma unroll
  for (int nt = 0; nt < 4; ++nt) {
    const __bf16* wrow = wt + ((j * 64 + nt * 16 + c) << 6);
    bfA0[nt] = *(const bf16x8*)(wrow + q * 8);
    bfA1[nt] = *(const bf16x8*)(wrow + 32 + q * 8);
  }

  // ---- 2-deep pipelined bin loop ------------------------------------------
  while (j < K_VOL) {
    const int jn = j + 4, jf = j + 8;
    const bool hasn = jn < K_VOL, hasf = jf < K_VOL;

    // 1. issue gathers for bin jn NOW (entries arrived; full-bin cover)
    bf16x8 pa00, pa01, pa10, pa11, pa20, pa21, pa30, pa31;
    if (hasn) {
      grow(x0, pa00, pa01); grow(x1, pa10, pa11);
      grow(x2, pa20, pa21); grow(x3, pa30, pa31);
    }

    // 2. issue cnt + entry loads for bin jf (two bins of cover)
    unsigned fc = 0, h0 = SENT, h1 = SENT, h2 = SENT, h3 = SENT;
    if (hasf) {
      fc = cnt[(b << 5) + jf];
      const unsigned* bpf = entries + (size_t)(b * K_VOL + jf) * CAP;
      h0 = bpf[c]; h1 = bpf[16 + c]; h2 = bpf[32 + c]; h3 = bpf[48 + c];
    }

    // 3. compute bin j
    if (ec) do_tile(w0, w1, qa00, qa01, qa10, qa11);
    if (ec > 32) do_tile(w2, w3, qa20, qa21, qa30, qa31);
    for (unsigned tb = 64; tb < ec; tb += 32) {   // rare overflow (P~1e-4)
      const unsigned* base = entries + (size_t)(b * K_VOL + j) * CAP;
      unsigned i0 = tb + c, i1 = tb + 16 + c;
      unsigned e0 = (i0 < ec) ? base[i0] : SENT;
      unsigned e1 = (i1 < ec) ? base[i1] : SENT;
      bf16x8 y00, y01, y10, y11;
      grow(e0, y00, y01);
      grow(e1, y10, y11);
      do_tile(e0, e1, y00, y01, y10, y11);
    }

    // 4. reload bfrag for jn AFTER its last use this bin
    if (hasn) {
#pragma unroll
      for (int nt = 0; nt < 4; ++nt) {
        const __bf16* wrow = wt + ((jn * 64 + nt * 16 + c) << 6);
        bfA0[nt] = *(const bf16x8*)(wrow + q * 8);
        bfA1[nt] = *(const bf16x8*)(wrow + 32 + q * 8);
      }
    }

    // 5. rotate
    ec = ecn;
    w0 = x0; w1 = x1; w2 = x2; w3 = x3;
    qa00 = pa00; qa01 = pa01; qa10 = pa10; qa11 = pa11;
    qa20 = pa20; qa21 = pa21; qa30 = pa30; qa31 = pa31;
    ecn = fc > CAP ? (unsigned)CAP : fc;
    x0 = ((unsigned)c < ecn) ? h0 : SENT;
    x1 = ((unsigned)(16 + c) < ecn) ? h1 : SENT;
    x2 = ((unsigned)(32 + c) < ecn) ? h2 : SENT;
    x3 = ((unsigned)(48 + c) < ecn) ? h3 : SENT;
    j = jn;
  }

  // ---- cross-wave reduce: 4 partial 64x64 f32 tiles -> wave 0, store ----
  __syncthreads();
  float* bufA = (float*)lds;              // 16 KB
  float* bufB = (float*)(lds + 16384);    // 16 KB

  auto REDST = [&](float* buf) {
#pragma unroll
    for (int rb = 0; rb < 4; ++rb)
#pragma unroll
      for (int nt = 0; nt < 4; ++nt)
#pragma unroll
        for (int r = 0; r < 4; ++r) {
          int row = rb * 16 + q * 4 + r;
          int col = (nt * 16 + c) ^ (q << 2) ^ ((q & 1) << 4);
          buf[row * 64 + col] = acc[rb][nt][r];
        }
  };
  auto REDADD = [&](const float* buf) {
#pragma unroll
    for (int rb = 0; rb < 4; ++rb)
#pragma unroll
      for (int nt = 0; nt < 4; ++nt)
#pragma unroll
        for (int r = 0; r < 4; ++r) {
          int row = rb * 16 + q * 4 + r;
          int col = (nt * 16 + c) ^ (q << 2) ^ ((q & 1) << 4);
          acc[rb][nt][r] += buf[row * 64 + col];
        }
  };

  if (wave == 1) REDST(bufA);
  if (wave == 3) REDST(bufB);
  __syncthreads();
  if (wave == 0) REDADD(bufA);
  if (wave == 2) REDADD(bufB);
  __syncthreads();
  if (wave == 2) REDST(bufA);
  __syncthreads();
  if (wave == 0) {
    REDADD(bufA);
    float bv[4];
#pragma unroll
    for (int nt = 0; nt < 4; ++nt) bv[nt] = bias[nt * 16 + c];
#pragma unroll
    for (int rb = 0; rb < 4; ++rb)
#pragma unroll
      for (int r = 0; r < 4; ++r) {
        const int row = b * RPB + rb * 16 + q * 4 + r;
        if (row < N_POINTS) {
#pragma unroll
          for (int nt = 0; nt < 4; ++nt)
            out[row * CCH + nt * 16 + c] = acc[rb][nt][r] + bv[nt];
        }
      }
  }
}

// ============================ fallback path (original) ============================

__global__ __launch_bounds__(256) void init_out_kernel(
    const float* __restrict__ bias, float* __restrict__ out) {
  int tid = blockIdx.x * blockDim.x + threadIdx.x;
  int c4 = tid & 15;
  float4 b = ((const float4*)bias)[c4];
  ((float4*)out)[tid] = b;
}

__global__ __launch_bounds__(256) void spconv_kernel(
    const float* __restrict__ input, const float* __restrict__ weight,
    const int* __restrict__ in_map, const int* __restrict__ out_map,
    float* __restrict__ out) {
  const int k = blockIdx.y;
  const int lane = threadIdx.x & 63;
  const int wave = threadIdx.x >> 6;
  const int col = lane & 15;
  const int quad = lane >> 4;

  const float* Wk = weight + k * (CCH * CCH);
  bf16x8 bfrag[4][2];
#pragma unroll
  for (int nt = 0; nt < 4; ++nt) {
    int co = nt * 16 + col;
#pragma unroll
    for (int s = 0; s < 2; ++s) {
      int ci0 = s * 32 + quad * 8;
      bf16x8 f;
#pragma unroll
      for (int j = 0; j < 8; ++j) f[j] = (__bf16)Wk[(ci0 + j) * CCH + co];
      bfrag[nt][s] = f;
    }
  }

  const int* im = in_map + k * PAIRS;
  const int* om = out_map + k * PAIRS;

  for (int tile = blockIdx.x * NWAVES + wave; tile < TILES_PER_K;
       tile += BX * NWAVES) {
    const int pbase = tile * 16;
    int rin = im[pbase + col];
    const float* arow = input + rin * CCH;
    bf16x8 afrag[2];
#pragma unroll
    for (int s = 0; s < 2; ++s) {
      const float4 x0 = *(const float4*)(arow + s * 32 + quad * 8);
      const float4 x1 = *(const float4*)(arow + s * 32 + quad * 8 + 4);
      bf16x8 f;
      f[0] = (__bf16)x0.x; f[1] = (__bf16)x0.y;
      f[2] = (__bf16)x0.z; f[3] = (__bf16)x0.w;
      f[4] = (__bf16)x1.x; f[5] = (__bf16)x1.y;
      f[6] = (__bf16)x1.z; f[7] = (__bf16)x1.w;
      afrag[s] = f;
    }

    f32x4 acc[4];
#pragma unroll
    for (int nt = 0; nt < 4; ++nt) acc[nt] = (f32x4){0.f, 0.f, 0.f, 0.f};
#pragma unroll
    for (int nt = 0; nt < 4; ++nt) {
      acc[nt] = __builtin_amdgcn_mfma_f32_16x16x32_bf16(afrag[0], bfrag[nt][0],
                                                        acc[nt], 0, 0, 0);
      acc[nt] = __builtin_amdgcn_mfma_f32_16x16x32_bf16(afrag[1], bfrag[nt][1],
                                                        acc[nt], 0, 0, 0);
    }

    int orow[4];
#pragma unroll
    for (int r = 0; r < 4; ++r) orow[r] = om[pbase + quad * 4 + r];
#pragma unroll
    for (int r = 0; r < 4; ++r) {
      float* op = out + orow[r] * CCH + col;
#pragma unroll
      for (int nt = 0; nt < 4; ++nt) atomicAdd(op + nt * 16, acc[nt][r]);
    }
  }
}

// ============================ launch ============================

extern "C" void kernel_launch(void* const* d_in, const int* in_sizes, int n_in,
                              void* d_out, int out_size, void* d_ws,
                              size_t ws_size, hipStream_t stream) {
  const float* input = (const float*)d_in[0];
  const float* weight = (const float*)d_in[1];
  const float* bias = (const float*)d_in[2];
  const int* in_map = (const int*)d_in[3];
  const int* out_map = (const int*)d_in[4];
  float* out = (float*)d_out;

  if (d_ws != nullptr && ws_size >= (size_t)WS_NEED) {
    unsigned char* ws = (unsigned char*)d_ws;
    hipMemsetAsync(ws + WS_CNT, 0, NBUCKETS * CNTSTRIDE * 4, stream);
    prep_fill_kernel<<<PREP_BLKS + FILL_BLKS, 256, 0, stream>>>(
        input, weight, in_map, out_map, ws);
    spconv_main_kernel<<<NBUCKETS, 256, 0, stream>>>(bias, ws, out);
  } else {
    init_out_kernel<<<(N_POINTS * 16) / 256, 256, 0, stream>>>(bias, out);
    dim3 grid(BX, K_VOL);
    spconv_kernel<<<grid, 256, 0, stream>>>(input, weight, in_map, out_map, out);
  }
}

// Round 14
// 215.043 us; speedup vs baseline: 3.0088x; 1.0567x over previous
//
#include <hip/hip_runtime.h>
#include <hip/hip_bf16.h>

#define N_POINTS 100000
#define K_VOL 27
#define PAIRS 60000
#define CCH 64                       // C_IN == C_OUT == 64
#define TILES_PER_K (PAIRS / 16)     // fallback path
#define BX 64                        // fallback path
#define NWAVES 4                     // fallback path

#define RPB 64                                     // rows per output bucket
#define NBUCKETS ((N_POINTS + RPB - 1) / RPB)      // 1563
#define NBINS (NBUCKETS * K_VOL)                   // 42201
#define CAP 96                                     // bin capacity (lambda=38.4)
#define SENT 0xFFFFFFFFu
#define CNTSTRIDE 32                               // counters padded to 128B/bucket

#define PREP_BLKS 6250                             // 1.6M threads for input cvt
#define FILL_BLKS (K_VOL * 64)                     // 1728: per k, 8 slices x 8 subs
#define PSUB (PAIRS / 8)                           // 7500 pairs per sub-range
#define NLB 200                                    // local buckets per slice (<=196)
#define CAPL 24                                    // LDS cell cap (lambda=4.8, P(>24)~1e-10)

// workspace layout (bytes)
#define WS_ENT 0
#define WS_CNT (NBINS * CAP * 4)                   // 16,205,184 (128B-aligned)
#define WS_INBF (WS_CNT + NBUCKETS * CNTSTRIDE * 4) // 16,405,248
#define WS_WT (WS_INBF + N_POINTS * CCH * 2)       // 29,205,248
#define WS_NEED (WS_WT + K_VOL * CCH * CCH * 2)    // 29,426,432 (~28.1 MiB)

typedef __bf16 bf16x8 __attribute__((ext_vector_type(8)));
typedef __bf16 bf16x4 __attribute__((ext_vector_type(4)));
typedef float f32x4 __attribute__((ext_vector_type(4)));

// ============================ new path ============================

// Fused prep + XCD-local fill (counters pre-zeroed by hipMemsetAsync).
// Fill (R14): SINGLE-pass LDS-buffered binning:
//   scan maps ONCE; matching entries buffered in LDS per cell (cap CAPL,
//   overflow -> direct global path, correct but rare ~1e-10/cell);
//   one global atomicAdd per nonzero cell reserves the bin range;
//   burst-copy LDS entries to global. Halves map traffic vs R12/R13
//   two-pass (156->104MB) and keeps ~330K global atomics.
// Slicing (bucket&7 pinned to one XCD via round-robin block ids) retained
// from R10. entry = in_row (17b) | out_local (6b) << 17
__global__ __launch_bounds__(256) void prep_fill_kernel(
    const float* __restrict__ input, const float* __restrict__ weight,
    const int* __restrict__ in_map, const int* __restrict__ out_map,
    unsigned char* __restrict__ ws) {
  const int bid = blockIdx.x;
  if (bid < PREP_BLKS) {
    int t = bid * 256 + threadIdx.x;  // exactly N*CCH/4 = 1,600,000 threads
    float4 v = ((const float4*)input)[t];
    bf16x4 o;
    o[0] = (__bf16)v.x; o[1] = (__bf16)v.y; o[2] = (__bf16)v.z; o[3] = (__bf16)v.w;
    *(bf16x4*)(ws + WS_INBF + (size_t)t * 8) = o;
    if (t < K_VOL * CCH * CCH) {             // 110592
      int k = t >> 12;
      int r = t & 4095;
      int ci = r >> 6, co = r & 63;
      *(__bf16*)(ws + WS_WT + (size_t)(((k * 64 + co) << 6) + ci) * 2) =
          (__bf16)weight[t];
    }
  } else {
    __shared__ unsigned int lcnt[NLB];
    __shared__ unsigned int lcur[NLB];
    __shared__ unsigned int lbuf[NLB * CAPL];    // 19,200 B
    const int f = bid - PREP_BLKS;               // [0, 1728)
    const int k = f >> 6;
    const int bx = f & 63;
    const int slice = bx & 7;
    const int sub = bx >> 3;
    const int pbeg = sub * PSUB, pend = pbeg + PSUB;
    const int* omp_ = out_map + k * PAIRS;
    const int* imp_ = in_map + k * PAIRS;
    unsigned int* cntp = (unsigned int*)(ws + WS_CNT);
    unsigned int* entp = (unsigned int*)(ws + WS_ENT);

    for (int i = threadIdx.x; i < NLB; i += 256) lcnt[i] = 0;
    __syncthreads();

    // single pass: buffer matching entries in LDS cells
    for (int p = pbeg + (int)threadIdx.x * 4; p < pend; p += 1024) {
      int4 om4 = *(const int4*)(omp_ + p);
      int4 im4 = *(const int4*)(imp_ + p);
      int oms[4] = {om4.x, om4.y, om4.z, om4.w};
      int ims[4] = {im4.x, im4.y, im4.z, im4.w};
#pragma unroll
      for (int j = 0; j < 4; ++j) {
        int bkt = oms[j] >> 6;
        if ((bkt & 7) != slice) continue;
        int lb = bkt >> 3;
        unsigned ent = (unsigned)ims[j] | ((unsigned)(oms[j] & 63) << 17);
        unsigned pos = atomicAdd(&lcnt[lb], 1u);
        if (pos < CAPL) {
          lbuf[lb * CAPL + pos] = ent;
        } else {
          // overflow fallback: direct global bump (correct, ~never taken)
          atomicSub(&lcnt[lb], 1u);
          unsigned gp = atomicAdd(cntp + (bkt << 5) + k, 1u);
          if (gp < CAP) entp[(size_t)(bkt * K_VOL + k) * CAP + gp] = ent;
        }
      }
    }
    __syncthreads();

    // reserve: ONE global atomic per nonzero cell
    for (int lb = threadIdx.x; lb < NLB; lb += 256) {
      unsigned n = lcnt[lb];
      if (n) {
        int bkt = (lb << 3) | slice;
        lcur[lb] = atomicAdd(cntp + (bkt << 5) + k, n);
      }
    }
    __syncthreads();

    // burst-copy LDS entries to the reserved global ranges
    for (int lb = threadIdx.x; lb < NLB; lb += 256) {
      unsigned n = lcnt[lb];
      if (!n) continue;
      int bkt = (lb << 3) | slice;
      unsigned base = lcur[lb];
      unsigned int* dst = entp + (size_t)(bkt * K_VOL + k) * CAP;
      for (unsigned i = 0; i < n; ++i) {
        unsigned pos = base + i;
        if (pos < CAP) dst[pos] = lbuf[lb * CAPL + i];
      }
    }
  }
}

// One block per 64-row bucket; per-wave 2-DEEP software-pipelined bin loop
// (verified R13). R14 change: LDS swizzle index (row&3) -> ((row>>1)&3) at
// all four sites (stage write / bb read / pa read / pmat mark+unmark).
// Derivation: with (row&3), a 16-lane c-scan lands on 4 b128 start-banks
// (4-way conflict, SQ_LDS_BANK_CONFLICT 1.007e7 constant since R7); with
// ((row>>1)&3) it covers 8 start-banks -> 2-way, which is free (m136).
// Write and read use the SAME function of row -> correctness preserved.
// NOTE: no min-waves bound -- capping unified regs spills the 64-AGPR acc
// (R8: 4.6x slowdown). Spill canary: WRITE_SIZE must stay 25MB.
__global__ __launch_bounds__(256) void spconv_main_kernel(
    const float* __restrict__ bias, const unsigned char* __restrict__ ws,
    float* __restrict__ out) {
  __shared__ __align__(16) unsigned char lds[4 * 8192];   // 32,768 B
  const unsigned int* cnt = (const unsigned int*)(ws + WS_CNT);
  const unsigned int* entries = (const unsigned int*)(ws + WS_ENT);
  const __bf16* inbf = (const __bf16*)(ws + WS_INBF);
  const __bf16* wt = (const __bf16*)(ws + WS_WT);

  const int b = blockIdx.x;
  const int tid = threadIdx.x;
  const int wave = tid >> 6, lane = tid & 63;
  const int c = lane & 15, q = lane >> 4;
  unsigned char* stage = lds + wave * 8192;
  unsigned char* pmat = stage + 4096;

  // zero this wave's pmat ONCE: b32 stride-1 across lanes = conflict-free
#pragma unroll
  for (int i = 0; i < 16; ++i)
    *(float*)(pmat + i * 256 + lane * 4) = 0.f;

  f32x4 acc[4][4];
#pragma unroll
  for (int rb = 0; rb < 4; ++rb)
#pragma unroll
    for (int nt = 0; nt < 4; ++nt) acc[rb][nt] = (f32x4){0.f, 0.f, 0.f, 0.f};

  bf16x8 bfA0[4], bfA1[4];   // current bin's B fragments

  auto grow = [&](unsigned v, bf16x8& x0, bf16x8& x1) {
    unsigned r = (v == SENT) ? 0u : (v & 0x1FFFFu);
    const __bf16* ar = inbf + ((size_t)r << 6);
    x0 = *(const bf16x8*)(ar + q * 8);
    x1 = *(const bf16x8*)(ar + 32 + q * 8);
  };

  // one 32-entry tile: mark -> C1 -> stage -> scatter -> unmark
  auto do_tile = [&](unsigned entL, unsigned entH, bf16x8 aL0, bf16x8 aL1,
                     bf16x8 aH0, bf16x8 aH1) {
    int mol0 = -1, mol1 = -1;
    if (q == 0 && entL != SENT) mol0 = (int)(entL >> 17);
    if (q == 1 && entH != SENT) mol1 = (int)(entH >> 17);
    if (mol0 >= 0) {
      int m = c;
      *(__bf16*)(pmat + mol0 * 64 + (((m >> 3) ^ ((mol0 >> 1) & 3)) << 4) +
                 (m & 7) * 2) = (__bf16)1.0f;
    }
    if (mol1 >= 0) {
      int m = 16 + c;
      *(__bf16*)(pmat + mol1 * 64 + (((m >> 3) ^ ((mol1 >> 1) & 3)) << 4) +
                 (m & 7) * 2) = (__bf16)1.0f;
    }

    f32x4 c1a[4], c1b[4];
#pragma unroll
    for (int nt = 0; nt < 4; ++nt) {
      c1a[nt] = (f32x4){0.f, 0.f, 0.f, 0.f};
      c1b[nt] = (f32x4){0.f, 0.f, 0.f, 0.f};
    }
#pragma unroll
    for (int nt = 0; nt < 4; ++nt) {
      c1a[nt] = __builtin_amdgcn_mfma_f32_16x16x32_bf16(aL0, bfA0[nt], c1a[nt],
                                                        0, 0, 0);
      c1a[nt] = __builtin_amdgcn_mfma_f32_16x16x32_bf16(aL1, bfA1[nt], c1a[nt],
                                                        0, 0, 0);
      c1b[nt] = __builtin_amdgcn_mfma_f32_16x16x32_bf16(aH0, bfA0[nt], c1b[nt],
                                                        0, 0, 0);
      c1b[nt] = __builtin_amdgcn_mfma_f32_16x16x32_bf16(aH1, bfA1[nt], c1b[nt],
                                                        0, 0, 0);
    }

    // stage C1 as bf16: [n:64][m:32], 16B-slot XOR swizzle (slot ^= (n>>1)&3)
#pragma unroll
    for (int nt = 0; nt < 4; ++nt) {
      const int n = nt * 16 + c;
      const int swz = (n >> 1) & 3;
      const int in0 = (q & 1) * 8;
      bf16x4 h0, h1;
#pragma unroll
      for (int r = 0; r < 4; ++r) {
        h0[r] = (__bf16)c1a[nt][r];
        h1[r] = (__bf16)c1b[nt][r];
      }
      *(bf16x4*)(stage + n * 64 + (((q >> 1) ^ swz) << 4) + in0) = h0;
      *(bf16x4*)(stage + n * 64 + (((2 + (q >> 1)) ^ swz) << 4) + in0) = h1;
    }

    bf16x8 pfrag[4];
#pragma unroll
    for (int rb = 0; rb < 4; ++rb)
      pfrag[rb] = *(const bf16x8*)(pmat + (rb * 16 + c) * 64 +
                                   ((q ^ ((c >> 1) & 3)) << 4));
#pragma unroll
    for (int nt = 0; nt < 4; ++nt) {
      const int n = nt * 16 + c;
      const bf16x8 bb = *(const bf16x8*)(stage + n * 64 +
                                         ((q ^ ((n >> 1) & 3)) << 4));
#pragma unroll
      for (int rb = 0; rb < 4; ++rb)
        acc[rb][nt] = __builtin_amdgcn_mfma_f32_16x16x32_bf16(pfrag[rb], bb,
                                                             acc[rb][nt], 0, 0, 0);
    }

    if (mol0 >= 0) {
      int m = c;
      *(__bf16*)(pmat + mol0 * 64 + (((m >> 3) ^ ((mol0 >> 1) & 3)) << 4) +
                 (m & 7) * 2) = (__bf16)0.0f;
    }
    if (mol1 >= 0) {
      int m = 16 + c;
      *(__bf16*)(pmat + mol1 * 64 + (((m >> 3) ^ ((mol1 >> 1) & 3)) << 4) +
                 (m & 7) * 2) = (__bf16)0.0f;
    }
  };

  // ---- prologue: bin j ready; bin j+4 entries masked ----------------------
  int j = wave;
  unsigned ec, w0, w1, w2, w3;                                 // bin j
  bf16x8 qa00, qa01, qa10, qa11, qa20, qa21, qa30, qa31;
  unsigned ecn, x0, x1, x2, x3;                                // bin j+4
  {
    unsigned cn0 = cnt[(b << 5) + j];
    const unsigned* bp0 = entries + (size_t)(b * K_VOL + j) * CAP;
    unsigned a0 = bp0[c], a1 = bp0[16 + c], a2 = bp0[32 + c], a3 = bp0[48 + c];
    unsigned cn1 = 0, b0 = SENT, b1 = SENT, b2 = SENT, b3 = SENT;
    if (j + 4 < K_VOL) {
      cn1 = cnt[(b << 5) + j + 4];
      const unsigned* bp1 = entries + (size_t)(b * K_VOL + j + 4) * CAP;
      b0 = bp1[c]; b1 = bp1[16 + c]; b2 = bp1[32 + c]; b3 = bp1[48 + c];
    }
    ec = cn0 > CAP ? (unsigned)CAP : cn0;
    w0 = ((unsigned)c < ec) ? a0 : SENT;
    w1 = ((unsigned)(16 + c) < ec) ? a1 : SENT;
    w2 = ((unsigned)(32 + c) < ec) ? a2 : SENT;
    w3 = ((unsigned)(48 + c) < ec) ? a3 : SENT;
    grow(w0, qa00, qa01); grow(w1, qa10, qa11);
    grow(w2, qa20, qa21); grow(w3, qa30, qa31);
    ecn = cn1 > CAP ? (unsigned)CAP : cn1;
    x0 = ((unsigned)c < ecn) ? b0 : SENT;
    x1 = ((unsigned)(16 + c) < ecn) ? b1 : SENT;
    x2 = ((unsigned)(32 + c) < ecn) ? b2 : SENT;
    x3 = ((unsigned)(48 + c) < ecn) ? b3 : SENT;
  }
#pragma unroll
  for (int nt = 0; nt < 4; ++nt) {
    const __bf16* wrow = wt + ((j * 64 + nt * 16 + c) << 6);
    bfA0[nt] = *(const bf16x8*)(wrow + q * 8);
    bfA1[nt] = *(const bf16x8*)(wrow + 32 + q * 8);
  }

  // ---- 2-deep pipelined bin loop ------------------------------------------
  while (j < K_VOL) {
    const int jn = j + 4, jf = j + 8;
    const bool hasn = jn < K_VOL, hasf = jf < K_VOL;

    // 1. issue gathers for bin jn NOW (entries arrived; full-bin cover)
    bf16x8 pa00, pa01, pa10, pa11, pa20, pa21, pa30, pa31;
    if (hasn) {
      grow(x0, pa00, pa01); grow(x1, pa10, pa11);
      grow(x2, pa20, pa21); grow(x3, pa30, pa31);
    }

    // 2. issue cnt + entry loads for bin jf (two bins of cover)
    unsigned fc = 0, h0 = SENT, h1 = SENT, h2 = SENT, h3 = SENT;
    if (hasf) {
      fc = cnt[(b << 5) + jf];
      const unsigned* bpf = entries + (size_t)(b * K_VOL + jf) * CAP;
      h0 = bpf[c]; h1 = bpf[16 + c]; h2 = bpf[32 + c]; h3 = bpf[48 + c];
    }

    // 3. compute bin j
    if (ec) do_tile(w0, w1, qa00, qa01, qa10, qa11);
    if (ec > 32) do_tile(w2, w3, qa20, qa21, qa30, qa31);
    for (unsigned tb = 64; tb < ec; tb += 32) {   // rare overflow (P~1e-4)
      const unsigned* base = entries + (size_t)(b * K_VOL + j) * CAP;
      unsigned i0 = tb + c, i1 = tb + 16 + c;
      unsigned e0 = (i0 < ec) ? base[i0] : SENT;
      unsigned e1 = (i1 < ec) ? base[i1] : SENT;
      bf16x8 y00, y01, y10, y11;
      grow(e0, y00, y01);
      grow(e1, y10, y11);
      do_tile(e0, e1, y00, y01, y10, y11);
    }

    // 4. reload bfrag for jn AFTER its last use this bin
    if (hasn) {
#pragma unroll
      for (int nt = 0; nt < 4; ++nt) {
        const __bf16* wrow = wt + ((jn * 64 + nt * 16 + c) << 6);
        bfA0[nt] = *(const bf16x8*)(wrow + q * 8);
        bfA1[nt] = *(const bf16x8*)(wrow + 32 + q * 8);
      }
    }

    // 5. rotate
    ec = ecn;
    w0 = x0; w1 = x1; w2 = x2; w3 = x3;
    qa00 = pa00; qa01 = pa01; qa10 = pa10; qa11 = pa11;
    qa20 = pa20; qa21 = pa21; qa30 = pa30; qa31 = pa31;
    ecn = fc > CAP ? (unsigned)CAP : fc;
    x0 = ((unsigned)c < ecn) ? h0 : SENT;
    x1 = ((unsigned)(16 + c) < ecn) ? h1 : SENT;
    x2 = ((unsigned)(32 + c) < ecn) ? h2 : SENT;
    x3 = ((unsigned)(48 + c) < ecn) ? h3 : SENT;
    j = jn;
  }

  // ---- cross-wave reduce: 4 partial 64x64 f32 tiles -> wave 0, store ----
  __syncthreads();
  float* bufA = (float*)lds;              // 16 KB
  float* bufB = (float*)(lds + 16384);    // 16 KB

  auto REDST = [&](float* buf) {
#pragma unroll
    for (int rb = 0; rb < 4; ++rb)
#pragma unroll
      for (int nt = 0; nt < 4; ++nt)
#pragma unroll
        for (int r = 0; r < 4; ++r) {
          int row = rb * 16 + q * 4 + r;
          int col = (nt * 16 + c) ^ (q << 2) ^ ((q & 1) << 4);
          buf[row * 64 + col] = acc[rb][nt][r];
        }
  };
  auto REDADD = [&](const float* buf) {
#pragma unroll
    for (int rb = 0; rb < 4; ++rb)
#pragma unroll
      for (int nt = 0; nt < 4; ++nt)
#pragma unroll
        for (int r = 0; r < 4; ++r) {
          int row = rb * 16 + q * 4 + r;
          int col = (nt * 16 + c) ^ (q << 2) ^ ((q & 1) << 4);
          acc[rb][nt][r] += buf[row * 64 + col];
        }
  };

  if (wave == 1) REDST(bufA);
  if (wave == 3) REDST(bufB);
  __syncthreads();
  if (wave == 0) REDADD(bufA);
  if (wave == 2) REDADD(bufB);
  __syncthreads();
  if (wave == 2) REDST(bufA);
  __syncthreads();
  if (wave == 0) {
    REDADD(bufA);
    float bv[4];
#pragma unroll
    for (int nt = 0; nt < 4; ++nt) bv[nt] = bias[nt * 16 + c];
#pragma unroll
    for (int rb = 0; rb < 4; ++rb)
#pragma unroll
      for (int r = 0; r < 4; ++r) {
        const int row = b * RPB + rb * 16 + q * 4 + r;
        if (row < N_POINTS) {
#pragma unroll
          for (int nt = 0; nt < 4; ++nt)
            out[row * CCH + nt * 16 + c] = acc[rb][nt][r] + bv[nt];
        }
      }
  }
}

// ============================ fallback path (original) ============================

__global__ __launch_bounds__(256) void init_out_kernel(
    const float* __restrict__ bias, float* __restrict__ out) {
  int tid = blockIdx.x * blockDim.x + threadIdx.x;
  int c4 = tid & 15;
  float4 b = ((const float4*)bias)[c4];
  ((float4*)out)[tid] = b;
}

__global__ __launch_bounds__(256) void spconv_kernel(
    const float* __restrict__ input, const float* __restrict__ weight,
    const int* __restrict__ in_map, const int* __restrict__ out_map,
    float* __restrict__ out) {
  const int k = blockIdx.y;
  const int lane = threadIdx.x & 63;
  const int wave = threadIdx.x >> 6;
  const int col = lane & 15;
  const int quad = lane >> 4;

  const float* Wk = weight + k * (CCH * CCH);
  bf16x8 bfrag[4][2];
#pragma unroll
  for (int nt = 0; nt < 4; ++nt) {
    int co = nt * 16 + col;
#pragma unroll
    for (int s = 0; s < 2; ++s) {
      int ci0 = s * 32 + quad * 8;
      bf16x8 f;
#pragma unroll
      for (int j = 0; j < 8; ++j) f[j] = (__bf16)Wk[(ci0 + j) * CCH + co];
      bfrag[nt][s] = f;
    }
  }

  const int* im = in_map + k * PAIRS;
  const int* om = out_map + k * PAIRS;

  for (int tile = blockIdx.x * NWAVES + wave; tile < TILES_PER_K;
       tile += BX * NWAVES) {
    const int pbase = tile * 16;
    int rin = im[pbase + col];
    const float* arow = input + rin * CCH;
    bf16x8 afrag[2];
#pragma unroll
    for (int s = 0; s < 2; ++s) {
      const float4 x0 = *(const float4*)(arow + s * 32 + quad * 8);
      const float4 x1 = *(const float4*)(arow + s * 32 + quad * 8 + 4);
      bf16x8 f;
      f[0] = (__bf16)x0.x; f[1] = (__bf16)x0.y;
      f[2] = (__bf16)x0.z; f[3] = (__bf16)x0.w;
      f[4] = (__bf16)x1.x; f[5] = (__bf16)x1.y;
      f[6] = (__bf16)x1.z; f[7] = (__bf16)x1.w;
      afrag[s] = f;
    }

    f32x4 acc[4];
#pragma unroll
    for (int nt = 0; nt < 4; ++nt) acc[nt] = (f32x4){0.f, 0.f, 0.f, 0.f};
#pragma unroll
    for (int nt = 0; nt < 4; ++nt) {
      acc[nt] = __builtin_amdgcn_mfma_f32_16x16x32_bf16(afrag[0], bfrag[nt][0],
                                                        acc[nt], 0, 0, 0);
      acc[nt] = __builtin_amdgcn_mfma_f32_16x16x32_bf16(afrag[1], bfrag[nt][1],
                                                        acc[nt], 0, 0, 0);
    }

    int orow[4];
#pragma unroll
    for (int r = 0; r < 4; ++r) orow[r] = om[pbase + quad * 4 + r];
#pragma unroll
    for (int r = 0; r < 4; ++r) {
      float* op = out + orow[r] * CCH + col;
#pragma unroll
      for (int nt = 0; nt < 4; ++nt) atomicAdd(op + nt * 16, acc[nt][r]);
    }
  }
}

// ============================ launch ============================

extern "C" void kernel_launch(void* const* d_in, const int* in_sizes, int n_in,
                              void* d_out, int out_size, void* d_ws,
                              size_t ws_size, hipStream_t stream) {
  const float* input = (const float*)d_in[0];
  const float* weight = (const float*)d_in[1];
  const float* bias = (const float*)d_in[2];
  const int* in_map = (const int*)d_in[3];
  const int* out_map = (const int*)d_in[4];
  float* out = (float*)d_out;

  if (d_ws != nullptr && ws_size >= (size_t)WS_NEED) {
    unsigned char* ws = (unsigned char*)d_ws;
    hipMemsetAsync(ws + WS_CNT, 0, NBUCKETS * CNTSTRIDE * 4, stream);
    prep_fill_kernel<<<PREP_BLKS + FILL_BLKS, 256, 0, stream>>>(
        input, weight, in_map, out_map, ws);
    spconv_main_kernel<<<NBUCKETS, 256, 0, stream>>>(bias, ws, out);
  } else {
    init_out_kernel<<<(N_POINTS * 16) / 256, 256, 0, stream>>>(bias, out);
    dim3 grid(BX, K_VOL);
    spconv_kernel<<<grid, 256, 0, stream>>>(input, weight, in_map, out_map, out);
  }
}